// Round 1
// baseline (323.887 us; speedup 1.0000x reference)
//
#include <hip/hip_runtime.h>
#include <stdint.h>

typedef unsigned short u16;
typedef u16 u16x4 __attribute__((ext_vector_type(4)));
typedef unsigned int u32x4 __attribute__((ext_vector_type(4)));
typedef float f32x4 __attribute__((ext_vector_type(4)));
typedef __bf16 bf16x8 __attribute__((ext_vector_type(8)));

#define DEVI __device__ __forceinline__

DEVI u16 f2bf(float f) {
  uint32_t u = __builtin_bit_cast(uint32_t, f);
  u = (u + 0x7FFFu + ((u >> 16) & 1u)) >> 16;
  return (u16)u;
}
DEVI float bf2f(u16 h) {
  uint32_t u = ((uint32_t)h) << 16;
  return __builtin_bit_cast(float, u);
}
DEVI f32x4 mfma16(u32x4 a, u32x4 b, f32x4 c) {
  return __builtin_amdgcn_mfma_f32_16x16x32_bf16(
      __builtin_bit_cast(bf16x8, a), __builtin_bit_cast(bf16x8, b), c, 0, 0, 0);
}

#define AS1 __attribute__((address_space(1)))
#define AS3 __attribute__((address_space(3)))
DEVI void gload16(const void* g, void* l) {
  // CK-style addrspace cast via integer roundtrip; LDS dest is linear
  // (wave-uniform base + lane*16), swizzle handled on the GLOBAL source side.
  __builtin_amdgcn_global_load_lds((AS1 void*)(uintptr_t)g,
                                   (AS3 void*)(uint32_t)(uintptr_t)l, 16, 0, 0);
}

DEVI float wred(float v) {
#pragma unroll
  for (int m = 1; m < 64; m <<= 1) v += __shfl_xor(v, m);
  return v;
}

// ---------------- weight transpose fp32 -> bf16, Wt[N][K] = W[K][N] ----------------
__global__ __launch_bounds__(256) void k_transpose(const float* __restrict__ W,
                                                   u16* __restrict__ Wt, int Kr,
                                                   int Nc) {
  __shared__ float tile[64][65];
  int tid = threadIdx.x;
  int n0 = blockIdx.x * 64, k0 = blockIdx.y * 64;
#pragma unroll
  for (int i = 0; i < 16; i++) {
    int idx = i * 256 + tid;
    int r = idx >> 6, cc = idx & 63;
    tile[r][cc] = W[(size_t)(k0 + r) * Nc + n0 + cc];
  }
  __syncthreads();
#pragma unroll
  for (int i = 0; i < 16; i++) {
    int idx = i * 256 + tid;
    int r = idx >> 6, cc = idx & 63;  // r = n-local, cc = k-local
    Wt[(size_t)(n0 + r) * Kr + k0 + cc] = f2bf(tile[cc][r]);
  }
}

// ---------------- LN1: x[a,b,512] -> xn_perm[b*1024+a][512] bf16, xn_res[a*16+b][512] bf16
__global__ __launch_bounds__(256) void k_ln1(const float* __restrict__ x,
                                             const float* __restrict__ gam,
                                             const float* __restrict__ bet,
                                             u16* __restrict__ xn_perm,
                                             u16* __restrict__ xn_res) {
  int tid = threadIdx.x, wid = tid >> 6, lane = tid & 63;
  int row = blockIdx.x * 4 + wid;  // token = a*16+b
  const float* xr = x + (size_t)row * 512 + lane * 8;
  f32x4 v0 = *(const f32x4*)xr;
  f32x4 v1 = *(const f32x4*)(xr + 4);
  float s = 0.f, ss = 0.f;
#pragma unroll
  for (int j = 0; j < 4; j++) {
    s += v0[j] + v1[j];
    ss += v0[j] * v0[j] + v1[j] * v1[j];
  }
  s = wred(s);
  ss = wred(ss);
  float mean = s * (1.0f / 512.0f);
  float var = ss * (1.0f / 512.0f) - mean * mean;
  float rstd = rsqrtf(var + 1e-5f);
  const float* gp = gam + lane * 8;
  const float* bp = bet + lane * 8;
  f32x4 ga = *(const f32x4*)gp, gb = *(const f32x4*)(gp + 4);
  f32x4 ba = *(const f32x4*)bp, bb = *(const f32x4*)(bp + 4);
  u16x4 o0, o1;
#pragma unroll
  for (int j = 0; j < 4; j++) {
    o0[j] = f2bf((v0[j] - mean) * rstd * ga[j] + ba[j]);
    o1[j] = f2bf((v1[j] - mean) * rstd * gb[j] + bb[j]);
  }
  int b = row & 15, a = row >> 4;
  u16* pp = xn_perm + ((size_t)((b << 10) | a)) * 512 + lane * 8;
  *(u16x4*)pp = o0;
  *(u16x4*)(pp + 4) = o1;
  u16* pr = xn_res + (size_t)row * 512 + lane * 8;
  *(u16x4*)pr = o0;
  *(u16x4*)(pr + 4) = o1;
}

// ---------------- LN2: xt = LN(xn_res + ao) -> xt_bf [token][512]
__global__ __launch_bounds__(256) void k_ln2(const u16* __restrict__ xn,
                                             const u16* __restrict__ ao,
                                             const float* __restrict__ gam,
                                             const float* __restrict__ bet,
                                             u16* __restrict__ xt) {
  int tid = threadIdx.x, wid = tid >> 6, lane = tid & 63;
  int row = blockIdx.x * 4 + wid;
  size_t base = (size_t)row * 512 + lane * 8;
  u16x4 a0 = *(const u16x4*)&xn[base], a1 = *(const u16x4*)&xn[base + 4];
  u16x4 c0 = *(const u16x4*)&ao[base], c1 = *(const u16x4*)&ao[base + 4];
  float v[8];
#pragma unroll
  for (int j = 0; j < 4; j++) {
    v[j] = bf2f(a0[j]) + bf2f(c0[j]);
    v[4 + j] = bf2f(a1[j]) + bf2f(c1[j]);
  }
  float s = 0.f, ss = 0.f;
#pragma unroll
  for (int j = 0; j < 8; j++) {
    s += v[j];
    ss += v[j] * v[j];
  }
  s = wred(s);
  ss = wred(ss);
  float mean = s * (1.0f / 512.0f);
  float var = ss * (1.0f / 512.0f) - mean * mean;
  float rstd = rsqrtf(var + 1e-5f);
  const float* gp = gam + lane * 8;
  const float* bp = bet + lane * 8;
  u16x4 o0, o1;
#pragma unroll
  for (int j = 0; j < 4; j++) {
    o0[j] = f2bf((v[j] - mean) * rstd * gp[j] + bp[j]);
    o1[j] = f2bf((v[4 + j] - mean) * rstd * gp[4 + j] + bp[4 + j]);
  }
  u16* pr = xt + base;
  *(u16x4*)pr = o0;
  *(u16x4*)(pr + 4) = o1;
}

// ---------------- GEMM C = A * B^T, A[M][K] bf16, B[N][K] bf16, 128x128 tile, BK=64
// EPI 0: QKV -> q[b,h,a,dh], k[b,h,a,dh], vt[b,h,dh,a] (+bias per 512-chunk); m = b*1024+a
// EPI 1: FFN1 -> o0[m][1024] = bf16(gelu(acc + b0[n]))
// EPI 2: FFN2 -> outf[m][512] = acc + b0[n] + resid[m][512]
template <int EPI>
__global__ __launch_bounds__(256, 2) void k_gemm(
    const u16* __restrict__ A, const u16* __restrict__ B, int K,
    const float* __restrict__ b0, const float* __restrict__ b1,
    const float* __restrict__ b2, u16* __restrict__ o0, u16* __restrict__ o1,
    u16* __restrict__ o2, const u16* __restrict__ resid,
    float* __restrict__ outf) {
  __shared__ __align__(16) u16 As[128 * 64];
  __shared__ __align__(16) u16 Bs[128 * 64];
  const int tid = threadIdx.x;
  const int wid = tid >> 6, lane = tid & 63;
  const int g = lane >> 4, c = lane & 15;
  const int m0 = blockIdx.x * 128, n0 = blockIdx.y * 128;
  const int wr = (wid >> 1) * 64, wc = (wid & 1) * 64;
  const int srow = tid >> 3, scb = tid & 7;

  f32x4 acc[4][4];
  const f32x4 zero = {0.f, 0.f, 0.f, 0.f};
#pragma unroll
  for (int i = 0; i < 4; i++)
#pragma unroll
    for (int j = 0; j < 4; j++) acc[i][j] = zero;

  for (int k0 = 0; k0 < K; k0 += 64) {
    __syncthreads();
#pragma unroll
    for (int i = 0; i < 4; i++) {
      int row = i * 32 + srow;
      int col = ((scb ^ (row & 7)) << 3);  // source-side swizzle (rule #21)
      gload16(A + (size_t)(m0 + row) * K + k0 + col, &As[(i * 256 + tid) * 8]);
      gload16(B + (size_t)(n0 + row) * K + k0 + col, &Bs[(i * 256 + tid) * 8]);
    }
    __syncthreads();
#pragma unroll
    for (int kk = 0; kk < 2; kk++) {
      u32x4 af[4], bfr[4];
#pragma unroll
      for (int mi = 0; mi < 4; mi++) {
        int row = wr + mi * 16 + c;
        int cb = (kk * 4 + g) ^ (row & 7);
        af[mi] = *(const u32x4*)&As[row * 64 + cb * 8];
      }
#pragma unroll
      for (int ni = 0; ni < 4; ni++) {
        int row = wc + ni * 16 + c;
        int cb = (kk * 4 + g) ^ (row & 7);
        bfr[ni] = *(const u32x4*)&Bs[row * 64 + cb * 8];
      }
#pragma unroll
      for (int mi = 0; mi < 4; mi++)
#pragma unroll
        for (int ni = 0; ni < 4; ni++)
          acc[mi][ni] = mfma16(af[mi], bfr[ni], acc[mi][ni]);
    }
  }

  if constexpr (EPI == 0) {
#pragma unroll
    for (int mi = 0; mi < 4; mi++) {
#pragma unroll
      for (int ni = 0; ni < 4; ni++) {
        int n = n0 + wc + ni * 16 + c;
        int which = n >> 9, h = (n >> 6) & 7, dh = n & 63;
        const float* bp = (which == 0) ? b0 : (which == 1) ? b1 : b2;
        float bias = bp[n & 511];
        int mbase = m0 + wr + mi * 16 + g * 4;
        int bb = mbase >> 10, aa = mbase & 1023;
        int bh = bb * 8 + h;
        if (which < 2) {
          u16* dst = ((which == 0) ? o0 : o1) + ((size_t)bh * 1024 + aa) * 64 + dh;
#pragma unroll
          for (int r = 0; r < 4; r++) dst[(size_t)r * 64] = f2bf(acc[mi][ni][r] + bias);
        } else {
          u16x4 pk;
#pragma unroll
          for (int r = 0; r < 4; r++) pk[r] = f2bf(acc[mi][ni][r] + bias);
          *(u16x4*)(o2 + ((size_t)bh * 64 + dh) * 1024 + aa) = pk;
        }
      }
    }
  } else if constexpr (EPI == 1) {
#pragma unroll
    for (int mi = 0; mi < 4; mi++) {
#pragma unroll
      for (int ni = 0; ni < 4; ni++) {
        int n = n0 + wc + ni * 16 + c;
        float bias = b0[n];
#pragma unroll
        for (int r = 0; r < 4; r++) {
          int m = m0 + wr + mi * 16 + g * 4 + r;
          float v = acc[mi][ni][r] + bias;
          v = 0.5f * v * (1.0f + erff(v * 0.70710678118654752f));
          o0[(size_t)m * 1024 + n] = f2bf(v);
        }
      }
    }
  } else {
#pragma unroll
    for (int mi = 0; mi < 4; mi++) {
#pragma unroll
      for (int ni = 0; ni < 4; ni++) {
        int n = n0 + wc + ni * 16 + c;
        float bias = b0[n];
#pragma unroll
        for (int r = 0; r < 4; r++) {
          int m = m0 + wr + mi * 16 + g * 4 + r;
          float v = acc[mi][ni][r] + bias + bf2f(resid[(size_t)m * 512 + n]);
          outf[(size_t)m * 512 + n] = v;
        }
      }
    }
  }
}

// ---------------- Gram partials: per (chunk of 128 a, bh, which) -> G (64x64) + col sums
__global__ __launch_bounds__(256) void k_gram(const u16* __restrict__ q,
                                              const u16* __restrict__ k,
                                              float* __restrict__ part,
                                              float* __restrict__ part2) {
  __shared__ float T[128 * 64];
  int tid = threadIdx.x;
  int chunk = blockIdx.x, bh = blockIdx.y, which = blockIdx.z;
  const u16* src = (which == 0 ? q : k) + ((size_t)bh * 1024 + chunk * 128) * 64;
#pragma unroll
  for (int i = 0; i < 8; i++) {
    int e = (i * 256 + tid) * 4;
    u16x4 u = *(const u16x4*)&src[e];
    f32x4 f = {bf2f(u[0]), bf2f(u[1]), bf2f(u[2]), bf2f(u[3])};
    *(f32x4*)&T[e] = f;
  }
  __syncthreads();
  int i0 = (tid >> 4) * 4, j0 = (tid & 15) * 4;
  float accg[4][4] = {};
  for (int a = 0; a < 128; a++) {
    f32x4 qi = *(const f32x4*)&T[a * 64 + i0];
    f32x4 qj = *(const f32x4*)&T[a * 64 + j0];
#pragma unroll
    for (int ii = 0; ii < 4; ii++)
#pragma unroll
      for (int jj = 0; jj < 4; jj++) accg[ii][jj] += qi[ii] * qj[jj];
  }
  float* dst = part + ((((size_t)which * 128 + bh) * 8 + chunk) << 12);
#pragma unroll
  for (int ii = 0; ii < 4; ii++)
#pragma unroll
    for (int jj = 0; jj < 4; jj++) dst[(i0 + ii) * 64 + (j0 + jj)] = accg[ii][jj];
  if (tid < 64) {
    float s = 0.f;
    for (int a = 0; a < 128; a++) s += T[a * 64 + tid];
    part2[(((size_t)which * 128 + bh) * 8 + chunk) * 64 + tid] = s;
  }
}

// ---------------- per-bh reduction: sumsq = <Gq,Gk>, sum = sq . sk
__global__ __launch_bounds__(256) void k_gram_reduce(const float* __restrict__ part,
                                                     const float* __restrict__ part2,
                                                     float* __restrict__ stats) {
  int bh = blockIdx.x, tid = threadIdx.x;
  const float* pq = part + ((size_t)bh << 15);
  const float* pk = part + ((size_t)(128 + bh) << 15);
  float local = 0.f;
#pragma unroll
  for (int j4 = 0; j4 < 4; j4++) {
    int e = tid * 16 + j4 * 4;
    f32x4 gq = {0.f, 0.f, 0.f, 0.f}, gk = {0.f, 0.f, 0.f, 0.f};
#pragma unroll
    for (int cc = 0; cc < 8; cc++) {
      gq += *(const f32x4*)&pq[cc * 4096 + e];
      gk += *(const f32x4*)&pk[cc * 4096 + e];
    }
    f32x4 p = gq * gk;
    local += p[0] + p[1] + p[2] + p[3];
  }
  local = wred(local);
  __shared__ float red[4];
  if ((tid & 63) == 0) red[tid >> 6] = local;
  __syncthreads();
  float sumv = 0.f;
  if (tid < 64) {
    const float* p2q = part2 + (size_t)bh * 512;
    const float* p2k = part2 + (size_t)(128 + bh) * 512;
    float sq = 0.f, sk = 0.f;
#pragma unroll
    for (int cc = 0; cc < 8; cc++) {
      sq += p2q[cc * 64 + tid];
      sk += p2k[cc * 64 + tid];
    }
    sumv = wred(sq * sk);
  }
  if (tid == 0) {
    stats[bh * 2] = red[0] + red[1] + red[2] + red[3];
    stats[bh * 2 + 1] = sumv;
  }
}

__global__ void k_scaling(const float* __restrict__ stats, float* __restrict__ ch) {
  int h = threadIdx.x;
  if (h < 8) {
    float ssq = 0.f, sm = 0.f;
    for (int b = 0; b < 16; b++) {
      ssq += stats[(b * 8 + h) * 2];
      sm += stats[(b * 8 + h) * 2 + 1];
    }
    const float N = 16777216.0f;
    float var = (ssq - sm * sm / N) / (N - 1.0f);
    float sd = sqrtf(fmaxf(var, 0.0f));
    float scal = 8.0f * sqrtf(1.0f + sd);
    ch[h] = 1.4426950408889634f / scal;  // log2(e)/scaling
  }
}

// ---------------- flash attention: per (qtile 128, bh); 4 waves x 32 q-rows
__global__ __launch_bounds__(256, 2) void k_attn(const u16* __restrict__ q,
                                                 const u16* __restrict__ k,
                                                 const u16* __restrict__ vt,
                                                 const float* __restrict__ ch_arr,
                                                 u16* __restrict__ ao) {
  __shared__ __align__(16) u16 Ks[64 * 64];
  __shared__ __align__(16) u16 Vts[64 * 64];
  __shared__ __align__(16) u16 Ps[4][32 * 64];
  int tid = threadIdx.x, wid = tid >> 6, lane = tid & 63;
  int g = lane >> 4, c = lane & 15;
  int qt = blockIdx.x, bh = blockIdx.y;
  int b = bh >> 3, h = bh & 7;
  float chv = ch_arr[h];
  int q0 = qt * 128 + wid * 32;
  const u16* qbase = q + ((size_t)bh << 16);
  const u16* kbase = k + ((size_t)bh << 16);
  const u16* vbase = vt + ((size_t)bh << 16);

  u32x4 aq[2][2];
#pragma unroll
  for (int mi = 0; mi < 2; mi++)
#pragma unroll
    for (int kk = 0; kk < 2; kk++)
      aq[mi][kk] = *(const u32x4*)&qbase[(size_t)(q0 + mi * 16 + c) * 64 + kk * 32 + g * 8];

  const f32x4 zero = {0.f, 0.f, 0.f, 0.f};
  f32x4 acc[2][4], mrow[2], lrow[2];
#pragma unroll
  for (int mi = 0; mi < 2; mi++) {
    mrow[mi] = {-1e30f, -1e30f, -1e30f, -1e30f};
    lrow[mi] = zero;
#pragma unroll
    for (int nj = 0; nj < 4; nj++) acc[mi][nj] = zero;
  }
  const int srow = tid >> 3, scb = tid & 7;

  for (int t0 = 0; t0 < 1024; t0 += 64) {
    __syncthreads();
#pragma unroll
    for (int i = 0; i < 2; i++) {
      int row = i * 32 + srow;
      int col = ((scb ^ (row & 7)) << 3);
      gload16(kbase + (size_t)(t0 + row) * 64 + col, &Ks[(i * 256 + tid) * 8]);
      gload16(vbase + (size_t)row * 1024 + t0 + col, &Vts[(i * 256 + tid) * 8]);
    }
    __syncthreads();
    u32x4 kf[4][2];
#pragma unroll
    for (int nj = 0; nj < 4; nj++)
#pragma unroll
      for (int kk = 0; kk < 2; kk++) {
        int row = nj * 16 + c;
        int cb = (kk * 4 + g) ^ (row & 7);
        kf[nj][kk] = *(const u32x4*)&Ks[row * 64 + cb * 8];
      }
    f32x4 s[2][4];
#pragma unroll
    for (int mi = 0; mi < 2; mi++)
#pragma unroll
      for (int nj = 0; nj < 4; nj++) s[mi][nj] = zero;
#pragma unroll
    for (int mi = 0; mi < 2; mi++)
#pragma unroll
      for (int nj = 0; nj < 4; nj++)
#pragma unroll
        for (int kk = 0; kk < 2; kk++)
          s[mi][nj] = mfma16(aq[mi][kk], kf[nj][kk], s[mi][nj]);

#pragma unroll
    for (int mi = 0; mi < 2; mi++) {
#pragma unroll
      for (int nj = 0; nj < 4; nj++) s[mi][nj] *= chv;
      f32x4 mx = s[mi][0];
#pragma unroll
      for (int nj = 1; nj < 4; nj++)
#pragma unroll
        for (int r = 0; r < 4; r++) mx[r] = fmaxf(mx[r], s[mi][nj][r]);
#pragma unroll
      for (int d = 1; d < 16; d <<= 1)
#pragma unroll
        for (int r = 0; r < 4; r++) mx[r] = fmaxf(mx[r], __shfl_xor(mx[r], d));
      f32x4 mnew, al;
#pragma unroll
      for (int r = 0; r < 4; r++) {
        mnew[r] = fmaxf(mrow[mi][r], mx[r]);
        al[r] = exp2f(mrow[mi][r] - mnew[r]);
      }
      mrow[mi] = mnew;
      f32x4 rs = zero;
#pragma unroll
      for (int nj = 0; nj < 4; nj++)
#pragma unroll
        for (int r = 0; r < 4; r++) {
          float p = exp2f(s[mi][nj][r] - mnew[r]);
          s[mi][nj][r] = p;
          rs[r] += p;
        }
#pragma unroll
      for (int d = 1; d < 16; d <<= 1)
#pragma unroll
        for (int r = 0; r < 4; r++) rs[r] += __shfl_xor(rs[r], d);
      lrow[mi] = lrow[mi] * al + rs;
#pragma unroll
      for (int nj = 0; nj < 4; nj++) acc[mi][nj] *= al;
#pragma unroll
      for (int nj = 0; nj < 4; nj++)
#pragma unroll
        for (int r = 0; r < 4; r++) {
          int prow = mi * 16 + g * 4 + r;
          int pcol = nj * 16 + c;
          int idx = prow * 64 + ((((pcol >> 3) ^ (prow & 7))) << 3) + (pcol & 7);
          Ps[wid][idx] = f2bf(s[mi][nj][r]);
        }
    }
    u32x4 vf[4][2], pf[2][2];
#pragma unroll
    for (int nj = 0; nj < 4; nj++)
#pragma unroll
      for (int kk = 0; kk < 2; kk++) {
        int row = nj * 16 + c;
        int cb = (kk * 4 + g) ^ (row & 7);
        vf[nj][kk] = *(const u32x4*)&Vts[row * 64 + cb * 8];
      }
#pragma unroll
    for (int mi = 0; mi < 2; mi++)
#pragma unroll
      for (int kk = 0; kk < 2; kk++) {
        int prow = mi * 16 + c;
        int cb = (kk * 4 + g) ^ (prow & 7);
        pf[mi][kk] = *(const u32x4*)&Ps[wid][prow * 64 + cb * 8];
      }
#pragma unroll
    for (int mi = 0; mi < 2; mi++)
#pragma unroll
      for (int nj = 0; nj < 4; nj++)
#pragma unroll
        for (int kk = 0; kk < 2; kk++)
          acc[mi][nj] = mfma16(pf[mi][kk], vf[nj][kk], acc[mi][nj]);
  }
#pragma unroll
  for (int mi = 0; mi < 2; mi++) {
    f32x4 inv;
#pragma unroll
    for (int r = 0; r < 4; r++) inv[r] = 1.0f / lrow[mi][r];
#pragma unroll
    for (int nj = 0; nj < 4; nj++)
#pragma unroll
      for (int r = 0; r < 4; r++) {
        float o = acc[mi][nj][r] * inv[r];
        int aRow = q0 + mi * 16 + g * 4 + r;
        int col = h * 64 + nj * 16 + c;
        ao[((size_t)aRow * 16 + b) * 512 + col] = f2bf(o);
      }
  }
}

extern "C" void kernel_launch(void* const* d_in, const int* in_sizes, int n_in,
                              void* d_out, int out_size, void* d_ws, size_t ws_size,
                              hipStream_t stream) {
  const float* x = (const float*)d_in[0];
  const float* Wq = (const float*)d_in[1];
  const float* bq = (const float*)d_in[2];
  const float* Wk = (const float*)d_in[3];
  const float* bk = (const float*)d_in[4];
  const float* Wv = (const float*)d_in[5];
  const float* bv = (const float*)d_in[6];
  const float* g1 = (const float*)d_in[7];
  const float* be1 = (const float*)d_in[8];
  const float* g2 = (const float*)d_in[9];
  const float* be2 = (const float*)d_in[10];
  const float* W1 = (const float*)d_in[11];
  const float* bf1 = (const float*)d_in[12];
  const float* W2 = (const float*)d_in[13];
  const float* bf2v = (const float*)d_in[14];
  float* out = (float*)d_out;

  char* w = (char*)d_ws;
  size_t off = 0;
  auto alloc = [&](size_t bytes) -> void* {
    void* p = w + off;
    off += (bytes + 255) & ~(size_t)255;
    return p;
  };
  u16* xn_perm = (u16*)alloc(16384ull * 512 * 2);
  u16* xn_res = (u16*)alloc(16384ull * 512 * 2);
  u16* qb = (u16*)alloc(128ull * 1024 * 64 * 2);
  u16* kb = (u16*)alloc(128ull * 1024 * 64 * 2);
  u16* vtb = (u16*)alloc(128ull * 64 * 1024 * 2);
  u16* wqkv_t = (u16*)alloc(1536ull * 512 * 2);
  u16* w1t = (u16*)alloc(1024ull * 512 * 2);
  u16* w2t = (u16*)alloc(512ull * 1024 * 2);
  float* gram = (float*)alloc(2ull * 128 * 8 * 4096 * 4);
  u16* h_bf = (u16*)gram;  // overlay: gram dead before FFN1 writes h
  float* gram2 = (float*)alloc(2ull * 128 * 8 * 64 * 4);
  float* stats = (float*)alloc(128ull * 2 * 4);
  float* ch = (float*)alloc(64ull * 4);
  u16* ao_bf = (u16*)alloc(16384ull * 512 * 2);
  u16* xt_bf = (u16*)alloc(16384ull * 512 * 2);

  // weights -> bf16 transposed
  k_transpose<<<dim3(8, 8), 256, 0, stream>>>(Wq, wqkv_t, 512, 512);
  k_transpose<<<dim3(8, 8), 256, 0, stream>>>(Wk, wqkv_t + 512 * 512, 512, 512);
  k_transpose<<<dim3(8, 8), 256, 0, stream>>>(Wv, wqkv_t + 1024 * 512, 512, 512);
  k_transpose<<<dim3(16, 8), 256, 0, stream>>>(W1, w1t, 512, 1024);
  k_transpose<<<dim3(8, 16), 256, 0, stream>>>(W2, w2t, 1024, 512);

  k_ln1<<<4096, 256, 0, stream>>>(x, g1, be1, xn_perm, xn_res);

  k_gemm<0><<<dim3(128, 12), 256, 0, stream>>>(xn_perm, wqkv_t, 512, bq, bk, bv,
                                               qb, kb, vtb, nullptr, nullptr);

  k_gram<<<dim3(8, 128, 2), 256, 0, stream>>>(qb, kb, gram, gram2);
  k_gram_reduce<<<128, 256, 0, stream>>>(gram, gram2, stats);
  k_scaling<<<1, 64, 0, stream>>>(stats, ch);

  k_attn<<<dim3(8, 128), 256, 0, stream>>>(qb, kb, vtb, ch, ao_bf);

  k_ln2<<<4096, 256, 0, stream>>>(xn_res, ao_bf, g2, be2, xt_bf);

  k_gemm<1><<<dim3(128, 8), 256, 0, stream>>>(xt_bf, w1t, 512, bf1, nullptr,
                                              nullptr, h_bf, nullptr, nullptr,
                                              nullptr, nullptr);
  k_gemm<2><<<dim3(128, 4), 256, 0, stream>>>(h_bf, w2t, 1024, bf2v, nullptr,
                                              nullptr, nullptr, nullptr, nullptr,
                                              xt_bf, out);
  (void)in_sizes; (void)n_in; (void)out_size; (void)ws_size;
}

// Round 2
// 323.840 us; speedup vs baseline: 1.0001x; 1.0001x over previous
//
#include <hip/hip_runtime.h>
#include <stdint.h>

typedef unsigned short u16;
typedef u16 u16x4 __attribute__((ext_vector_type(4)));
typedef unsigned int u32x4 __attribute__((ext_vector_type(4)));
typedef float f32x4 __attribute__((ext_vector_type(4)));
typedef float f32x16 __attribute__((ext_vector_type(16)));
typedef __bf16 bf16x8 __attribute__((ext_vector_type(8)));

#define DEVI __device__ __forceinline__

DEVI u16 f2bf(float f) {
  uint32_t u = __builtin_bit_cast(uint32_t, f);
  u = (u + 0x7FFFu + ((u >> 16) & 1u)) >> 16;
  return (u16)u;
}
DEVI float bf2f(u16 h) {
  uint32_t u = ((uint32_t)h) << 16;
  return __builtin_bit_cast(float, u);
}
DEVI f32x4 mfma16(u32x4 a, u32x4 b, f32x4 c) {
  return __builtin_amdgcn_mfma_f32_16x16x32_bf16(
      __builtin_bit_cast(bf16x8, a), __builtin_bit_cast(bf16x8, b), c, 0, 0, 0);
}
DEVI f32x16 mfma32(u32x4 a, u32x4 b, f32x16 c) {
  return __builtin_amdgcn_mfma_f32_32x32x16_bf16(
      __builtin_bit_cast(bf16x8, a), __builtin_bit_cast(bf16x8, b), c, 0, 0, 0);
}
DEVI uint32_t cvtpk(float lo, float hi) {
  uint32_t w;
  asm("v_cvt_pk_bf16_f32 %0, %1, %2" : "=v"(w) : "v"(lo), "v"(hi));
  return w;
}
DEVI void plswap(uint32_t& a, uint32_t& b) {
  asm("v_permlane32_swap_b32 %0, %1" : "+v"(a), "+v"(b));
}
DEVI float xmax2(float v) {  // max with lane^32 partner (both halves get result)
  uint32_t a = __builtin_bit_cast(uint32_t, v), b = a;
  plswap(a, b);
  return fmaxf(__builtin_bit_cast(float, a), __builtin_bit_cast(float, b));
}
DEVI float xadd2(float v) {
  uint32_t a = __builtin_bit_cast(uint32_t, v), b = a;
  plswap(a, b);
  return __builtin_bit_cast(float, a) + __builtin_bit_cast(float, b);
}

#define AS1 __attribute__((address_space(1)))
#define AS3 __attribute__((address_space(3)))
DEVI void gload16(const void* g, void* l) {
  __builtin_amdgcn_global_load_lds((AS1 void*)(uintptr_t)g,
                                   (AS3 void*)(uint32_t)(uintptr_t)l, 16, 0, 0);
}

DEVI float wred(float v) {
#pragma unroll
  for (int m = 1; m < 64; m <<= 1) v += __shfl_xor(v, m);
  return v;
}

// ---------------- weight transpose fp32 -> bf16, Wt[N][K] = W[K][N] ----------------
__global__ __launch_bounds__(256) void k_transpose(const float* __restrict__ W,
                                                   u16* __restrict__ Wt, int Kr,
                                                   int Nc) {
  __shared__ float tile[64][65];
  int tid = threadIdx.x;
  int n0 = blockIdx.x * 64, k0 = blockIdx.y * 64;
#pragma unroll
  for (int i = 0; i < 16; i++) {
    int idx = i * 256 + tid;
    int r = idx >> 6, cc = idx & 63;
    tile[r][cc] = W[(size_t)(k0 + r) * Nc + n0 + cc];
  }
  __syncthreads();
#pragma unroll
  for (int i = 0; i < 16; i++) {
    int idx = i * 256 + tid;
    int r = idx >> 6, cc = idx & 63;
    Wt[(size_t)(n0 + r) * Kr + k0 + cc] = f2bf(tile[cc][r]);
  }
}

// ---------------- LN1 ----------------
__global__ __launch_bounds__(256) void k_ln1(const float* __restrict__ x,
                                             const float* __restrict__ gam,
                                             const float* __restrict__ bet,
                                             u16* __restrict__ xn_perm,
                                             u16* __restrict__ xn_res) {
  int tid = threadIdx.x, wid = tid >> 6, lane = tid & 63;
  int row = blockIdx.x * 4 + wid;
  const float* xr = x + (size_t)row * 512 + lane * 8;
  f32x4 v0 = *(const f32x4*)xr;
  f32x4 v1 = *(const f32x4*)(xr + 4);
  float s = 0.f, ss = 0.f;
#pragma unroll
  for (int j = 0; j < 4; j++) {
    s += v0[j] + v1[j];
    ss += v0[j] * v0[j] + v1[j] * v1[j];
  }
  s = wred(s);
  ss = wred(ss);
  float mean = s * (1.0f / 512.0f);
  float var = ss * (1.0f / 512.0f) - mean * mean;
  float rstd = rsqrtf(var + 1e-5f);
  const float* gp = gam + lane * 8;
  const float* bp = bet + lane * 8;
  f32x4 ga = *(const f32x4*)gp, gb = *(const f32x4*)(gp + 4);
  f32x4 ba = *(const f32x4*)bp, bb = *(const f32x4*)(bp + 4);
  u16x4 o0, o1;
#pragma unroll
  for (int j = 0; j < 4; j++) {
    o0[j] = f2bf((v0[j] - mean) * rstd * ga[j] + ba[j]);
    o1[j] = f2bf((v1[j] - mean) * rstd * gb[j] + bb[j]);
  }
  int b = row & 15, a = row >> 4;
  u16* pp = xn_perm + ((size_t)((b << 10) | a)) * 512 + lane * 8;
  *(u16x4*)pp = o0;
  *(u16x4*)(pp + 4) = o1;
  u16* pr = xn_res + (size_t)row * 512 + lane * 8;
  *(u16x4*)pr = o0;
  *(u16x4*)(pr + 4) = o1;
}

// ---------------- LN2 ----------------
__global__ __launch_bounds__(256) void k_ln2(const u16* __restrict__ xn,
                                             const u16* __restrict__ ao,
                                             const float* __restrict__ gam,
                                             const float* __restrict__ bet,
                                             u16* __restrict__ xt) {
  int tid = threadIdx.x, wid = tid >> 6, lane = tid & 63;
  int row = blockIdx.x * 4 + wid;
  size_t base = (size_t)row * 512 + lane * 8;
  u16x4 a0 = *(const u16x4*)&xn[base], a1 = *(const u16x4*)&xn[base + 4];
  u16x4 c0 = *(const u16x4*)&ao[base], c1 = *(const u16x4*)&ao[base + 4];
  float v[8];
#pragma unroll
  for (int j = 0; j < 4; j++) {
    v[j] = bf2f(a0[j]) + bf2f(c0[j]);
    v[4 + j] = bf2f(a1[j]) + bf2f(c1[j]);
  }
  float s = 0.f, ss = 0.f;
#pragma unroll
  for (int j = 0; j < 8; j++) {
    s += v[j];
    ss += v[j] * v[j];
  }
  s = wred(s);
  ss = wred(ss);
  float mean = s * (1.0f / 512.0f);
  float var = ss * (1.0f / 512.0f) - mean * mean;
  float rstd = rsqrtf(var + 1e-5f);
  const float* gp = gam + lane * 8;
  const float* bp = bet + lane * 8;
  u16x4 o0, o1;
#pragma unroll
  for (int j = 0; j < 4; j++) {
    o0[j] = f2bf((v[j] - mean) * rstd * gp[j] + bp[j]);
    o1[j] = f2bf((v[4 + j] - mean) * rstd * gp[4 + j] + bp[4 + j]);
  }
  u16* pr = xt + base;
  *(u16x4*)pr = o0;
  *(u16x4*)(pr + 4) = o1;
}

// ---------------- GEMM C = A * B^T (unchanged from R1) ----------------
template <int EPI>
__global__ __launch_bounds__(256, 2) void k_gemm(
    const u16* __restrict__ A, const u16* __restrict__ B, int K,
    const float* __restrict__ b0, const float* __restrict__ b1,
    const float* __restrict__ b2, u16* __restrict__ o0, u16* __restrict__ o1,
    u16* __restrict__ o2, const u16* __restrict__ resid,
    float* __restrict__ outf) {
  __shared__ __align__(16) u16 As[128 * 64];
  __shared__ __align__(16) u16 Bs[128 * 64];
  const int tid = threadIdx.x;
  const int wid = tid >> 6, lane = tid & 63;
  const int g = lane >> 4, c = lane & 15;
  const int m0 = blockIdx.x * 128, n0 = blockIdx.y * 128;
  const int wr = (wid >> 1) * 64, wc = (wid & 1) * 64;
  const int srow = tid >> 3, scb = tid & 7;

  f32x4 acc[4][4];
  const f32x4 zero = {0.f, 0.f, 0.f, 0.f};
#pragma unroll
  for (int i = 0; i < 4; i++)
#pragma unroll
    for (int j = 0; j < 4; j++) acc[i][j] = zero;

  for (int k0 = 0; k0 < K; k0 += 64) {
    __syncthreads();
#pragma unroll
    for (int i = 0; i < 4; i++) {
      int row = i * 32 + srow;
      int col = ((scb ^ (row & 7)) << 3);
      gload16(A + (size_t)(m0 + row) * K + k0 + col, &As[(i * 256 + tid) * 8]);
      gload16(B + (size_t)(n0 + row) * K + k0 + col, &Bs[(i * 256 + tid) * 8]);
    }
    __syncthreads();
#pragma unroll
    for (int kk = 0; kk < 2; kk++) {
      u32x4 af[4], bfr[4];
#pragma unroll
      for (int mi = 0; mi < 4; mi++) {
        int row = wr + mi * 16 + c;
        int cb = (kk * 4 + g) ^ (row & 7);
        af[mi] = *(const u32x4*)&As[row * 64 + cb * 8];
      }
#pragma unroll
      for (int ni = 0; ni < 4; ni++) {
        int row = wc + ni * 16 + c;
        int cb = (kk * 4 + g) ^ (row & 7);
        bfr[ni] = *(const u32x4*)&Bs[row * 64 + cb * 8];
      }
#pragma unroll
      for (int mi = 0; mi < 4; mi++)
#pragma unroll
        for (int ni = 0; ni < 4; ni++)
          acc[mi][ni] = mfma16(af[mi], bfr[ni], acc[mi][ni]);
    }
  }

  if constexpr (EPI == 0) {
#pragma unroll
    for (int mi = 0; mi < 4; mi++) {
#pragma unroll
      for (int ni = 0; ni < 4; ni++) {
        int n = n0 + wc + ni * 16 + c;
        int which = n >> 9, h = (n >> 6) & 7, dh = n & 63;
        const float* bp = (which == 0) ? b0 : (which == 1) ? b1 : b2;
        float bias = bp[n & 511];
        int mbase = m0 + wr + mi * 16 + g * 4;
        int bb = mbase >> 10, aa = mbase & 1023;
        int bh = bb * 8 + h;
        if (which < 2) {
          u16* dst = ((which == 0) ? o0 : o1) + ((size_t)bh * 1024 + aa) * 64 + dh;
#pragma unroll
          for (int r = 0; r < 4; r++) dst[(size_t)r * 64] = f2bf(acc[mi][ni][r] + bias);
        } else {
          u16x4 pk;
#pragma unroll
          for (int r = 0; r < 4; r++) pk[r] = f2bf(acc[mi][ni][r] + bias);
          *(u16x4*)(o2 + ((size_t)bh * 64 + dh) * 1024 + aa) = pk;
        }
      }
    }
  } else if constexpr (EPI == 1) {
#pragma unroll
    for (int mi = 0; mi < 4; mi++) {
#pragma unroll
      for (int ni = 0; ni < 4; ni++) {
        int n = n0 + wc + ni * 16 + c;
        float bias = b0[n];
#pragma unroll
        for (int r = 0; r < 4; r++) {
          int m = m0 + wr + mi * 16 + g * 4 + r;
          float v = acc[mi][ni][r] + bias;
          v = 0.5f * v * (1.0f + erff(v * 0.70710678118654752f));
          o0[(size_t)m * 1024 + n] = f2bf(v);
        }
      }
    }
  } else {
#pragma unroll
    for (int mi = 0; mi < 4; mi++) {
#pragma unroll
      for (int ni = 0; ni < 4; ni++) {
        int n = n0 + wc + ni * 16 + c;
        float bias = b0[n];
#pragma unroll
        for (int r = 0; r < 4; r++) {
          int m = m0 + wr + mi * 16 + g * 4 + r;
          float v = acc[mi][ni][r] + bias + bf2f(resid[(size_t)m * 512 + n]);
          outf[(size_t)m * 512 + n] = v;
        }
      }
    }
  }
}

// ---------------- Gram partials (unchanged) ----------------
__global__ __launch_bounds__(256) void k_gram(const u16* __restrict__ q,
                                              const u16* __restrict__ k,
                                              float* __restrict__ part,
                                              float* __restrict__ part2) {
  __shared__ float T[128 * 64];
  int tid = threadIdx.x;
  int chunk = blockIdx.x, bh = blockIdx.y, which = blockIdx.z;
  const u16* src = (which == 0 ? q : k) + ((size_t)bh * 1024 + chunk * 128) * 64;
#pragma unroll
  for (int i = 0; i < 8; i++) {
    int e = (i * 256 + tid) * 4;
    u16x4 u = *(const u16x4*)&src[e];
    f32x4 f = {bf2f(u[0]), bf2f(u[1]), bf2f(u[2]), bf2f(u[3])};
    *(f32x4*)&T[e] = f;
  }
  __syncthreads();
  int i0 = (tid >> 4) * 4, j0 = (tid & 15) * 4;
  float accg[4][4] = {};
  for (int a = 0; a < 128; a++) {
    f32x4 qi = *(const f32x4*)&T[a * 64 + i0];
    f32x4 qj = *(const f32x4*)&T[a * 64 + j0];
#pragma unroll
    for (int ii = 0; ii < 4; ii++)
#pragma unroll
      for (int jj = 0; jj < 4; jj++) accg[ii][jj] += qi[ii] * qj[jj];
  }
  float* dst = part + ((((size_t)which * 128 + bh) * 8 + chunk) << 12);
#pragma unroll
  for (int ii = 0; ii < 4; ii++)
#pragma unroll
    for (int jj = 0; jj < 4; jj++) dst[(i0 + ii) * 64 + (j0 + jj)] = accg[ii][jj];
  if (tid < 64) {
    float s = 0.f;
    for (int a = 0; a < 128; a++) s += T[a * 64 + tid];
    part2[(((size_t)which * 128 + bh) * 8 + chunk) * 64 + tid] = s;
  }
}

__global__ __launch_bounds__(256) void k_gram_reduce(const float* __restrict__ part,
                                                     const float* __restrict__ part2,
                                                     float* __restrict__ stats) {
  int bh = blockIdx.x, tid = threadIdx.x;
  const float* pq = part + ((size_t)bh << 15);
  const float* pk = part + ((size_t)(128 + bh) << 15);
  float local = 0.f;
#pragma unroll
  for (int j4 = 0; j4 < 4; j4++) {
    int e = tid * 16 + j4 * 4;
    f32x4 gq = {0.f, 0.f, 0.f, 0.f}, gk = {0.f, 0.f, 0.f, 0.f};
#pragma unroll
    for (int cc = 0; cc < 8; cc++) {
      gq += *(const f32x4*)&pq[cc * 4096 + e];
      gk += *(const f32x4*)&pk[cc * 4096 + e];
    }
    f32x4 p = gq * gk;
    local += p[0] + p[1] + p[2] + p[3];
  }
  local = wred(local);
  __shared__ float red[4];
  if ((tid & 63) == 0) red[tid >> 6] = local;
  __syncthreads();
  float sumv = 0.f;
  if (tid < 64) {
    const float* p2q = part2 + (size_t)bh * 512;
    const float* p2k = part2 + (size_t)(128 + bh) * 512;
    float sq = 0.f, sk = 0.f;
#pragma unroll
    for (int cc = 0; cc < 8; cc++) {
      sq += p2q[cc * 64 + tid];
      sk += p2k[cc * 64 + tid];
    }
    sumv = wred(sq * sk);
  }
  if (tid == 0) {
    stats[bh * 2] = red[0] + red[1] + red[2] + red[3];
    stats[bh * 2 + 1] = sumv;
  }
}

__global__ void k_scaling(const float* __restrict__ stats, float* __restrict__ ch) {
  int h = threadIdx.x;
  if (h < 8) {
    float ssq = 0.f, sm = 0.f;
    for (int b = 0; b < 16; b++) {
      ssq += stats[(b * 8 + h) * 2];
      sm += stats[(b * 8 + h) * 2 + 1];
    }
    const float N = 16777216.0f;
    float var = (ssq - sm * sm / N) / (N - 1.0f);
    float sd = sqrtf(fmaxf(var, 0.0f));
    float scal = 8.0f * sqrtf(1.0f + sd);
    ch[h] = 1.4426950408889634f / scal;  // log2(e)/scaling
  }
}

// ---------------- flash attention, swapped-operand 32x32, zero LDS ----------------
// Per warp: 32 q rows. S^T = mfma32(K, Q): lane holds q=lane&31, 16 kv rows.
// O^T = mfma32(V^T, P^T): accumulator also q=lane&31 -> rescale fully in-lane.
struct KV {
  u32x4 k[4];
  u32x4 v[4];
};

DEVI void load_kv(const u16* __restrict__ kb, const u16* __restrict__ vb,
                  int kv0, int r, int h8, KV& f) {
  const u16* kp = kb + (size_t)(kv0 + r) * 64 + h8;
#pragma unroll
  for (int ks = 0; ks < 4; ks++) f.k[ks] = *(const u32x4*)(kp + ks * 16);
#pragma unroll
  for (int mt = 0; mt < 2; mt++)
#pragma unroll
    for (int ks = 0; ks < 2; ks++)
      f.v[mt * 2 + ks] =
          *(const u32x4*)(vb + (size_t)(mt * 32 + r) * 1024 + kv0 + ks * 16 + h8);
}

DEVI void attn_tile(const KV& f, const u32x4* qf, f32x16& o0, f32x16& o1,
                    float& m_run, float& l_run) {
  f32x16 st = {0.f, 0.f, 0.f, 0.f, 0.f, 0.f, 0.f, 0.f,
               0.f, 0.f, 0.f, 0.f, 0.f, 0.f, 0.f, 0.f};
#pragma unroll
  for (int ks = 0; ks < 4; ks++) st = mfma32(f.k[ks], qf[ks], st);
  // tile max: in-lane tree + cross-half swap
  float mx[8];
#pragma unroll
  for (int i = 0; i < 8; i++) mx[i] = fmaxf(st[i], st[i + 8]);
#pragma unroll
  for (int i = 0; i < 4; i++) mx[i] = fmaxf(mx[i], mx[i + 4]);
  float pm = fmaxf(fmaxf(mx[0], mx[2]), fmaxf(mx[1], mx[3]));
  pm = xmax2(pm);
  if (__any(pm > m_run + 8.0f)) {  // defer-max (T13)
    float mnew = fmaxf(m_run, pm);
    float al = exp2f(m_run - mnew);
    l_run *= al;
#pragma unroll
    for (int i = 0; i < 16; i++) {
      o0[i] *= al;
      o1[i] *= al;
    }
    m_run = mnew;
  }
  float p[16];
#pragma unroll
  for (int i = 0; i < 16; i++) p[i] = exp2f(st[i] - m_run);
  float sm[8];
#pragma unroll
  for (int i = 0; i < 8; i++) sm[i] = p[i] + p[i + 8];
#pragma unroll
  for (int i = 0; i < 4; i++) sm[i] += sm[i + 4];
  float rs = (sm[0] + sm[2]) + (sm[1] + sm[3]);
  l_run += xadd2(rs);
  // P^T -> bf16 B-fragments via cvt_pk + permlane32_swap
#pragma unroll
  for (int ks = 0; ks < 2; ks++) {
    uint32_t A0 = cvtpk(p[ks * 8 + 0], p[ks * 8 + 1]);
    uint32_t A1 = cvtpk(p[ks * 8 + 4], p[ks * 8 + 5]);
    plswap(A0, A1);
    uint32_t B0 = cvtpk(p[ks * 8 + 2], p[ks * 8 + 3]);
    uint32_t B1 = cvtpk(p[ks * 8 + 6], p[ks * 8 + 7]);
    plswap(B0, B1);
    u32x4 pa = {A0, B0, A1, B1};
    o0 = mfma32(f.v[ks], pa, o0);
    o1 = mfma32(f.v[2 + ks], pa, o1);
  }
}

__global__ __launch_bounds__(256) void k_attn(const u16* __restrict__ q,
                                              const u16* __restrict__ k,
                                              const u16* __restrict__ vt,
                                              const float* __restrict__ ch_arr,
                                              u16* __restrict__ ao) {
  int tid = threadIdx.x, wid = tid >> 6, lane = tid & 63;
  int r = lane & 31, hi = lane >> 5, h8 = hi * 8;
  int bh = blockIdx.x, qt = blockIdx.y;  // bh on x -> all q-tiles of a bh share an XCD
  int b = bh >> 3, h = bh & 7;
  float sc = ch_arr[h];
  int q0 = qt * 128 + wid * 32;
  const u16* qb = q + ((size_t)bh << 16);
  const u16* kb = k + ((size_t)bh << 16);
  const u16* vb = vt + ((size_t)bh << 16);

  // Q fragments, scaled by log2(e)/scaling, repacked to bf16
  u32x4 qf[4];
  const u16* qrow = qb + (size_t)(q0 + r) * 64 + h8;
#pragma unroll
  for (int ks = 0; ks < 4; ks++) {
    u32x4 raw = *(const u32x4*)(qrow + ks * 16);
    u32x4 w;
#pragma unroll
    for (int t = 0; t < 4; t++) {
      float lo = bf2f((u16)(raw[t] & 0xffffu)) * sc;
      float hi_ = bf2f((u16)(raw[t] >> 16)) * sc;
      w[t] = cvtpk(lo, hi_);
    }
    qf[ks] = w;
  }

  f32x16 o0 = {0.f, 0.f, 0.f, 0.f, 0.f, 0.f, 0.f, 0.f,
               0.f, 0.f, 0.f, 0.f, 0.f, 0.f, 0.f, 0.f};
  f32x16 o1 = o0;
  float m_run = -1e30f, l_run = 0.f;

  KV fA, fB;
  load_kv(kb, vb, 0, r, h8, fA);
  for (int t0 = 0; t0 < 1024; t0 += 64) {
    load_kv(kb, vb, t0 + 32, r, h8, fB);
    attn_tile(fA, qf, o0, o1, m_run, l_run);
    if (t0 + 64 < 1024) load_kv(kb, vb, t0 + 64, r, h8, fA);
    attn_tile(fB, qf, o0, o1, m_run, l_run);
  }

  float inv = 1.0f / l_run;
  int a_idx = q0 + r;
  u16* aop = ao + ((size_t)(a_idx * 16 + b)) * 512 + h * 64;
#pragma unroll
  for (int i = 0; i < 16; i++) {
    int dh0 = (i & 3) + 8 * (i >> 2) + 4 * hi;
    aop[dh0] = f2bf(o0[i] * inv);
    aop[32 + dh0] = f2bf(o1[i] * inv);
  }
}

extern "C" void kernel_launch(void* const* d_in, const int* in_sizes, int n_in,
                              void* d_out, int out_size, void* d_ws, size_t ws_size,
                              hipStream_t stream) {
  const float* x = (const float*)d_in[0];
  const float* Wq = (const float*)d_in[1];
  const float* bq = (const float*)d_in[2];
  const float* Wk = (const float*)d_in[3];
  const float* bk = (const float*)d_in[4];
  const float* Wv = (const float*)d_in[5];
  const float* bv = (const float*)d_in[6];
  const float* g1 = (const float*)d_in[7];
  const float* be1 = (const float*)d_in[8];
  const float* g2 = (const float*)d_in[9];
  const float* be2 = (const float*)d_in[10];
  const float* W1 = (const float*)d_in[11];
  const float* bf1 = (const float*)d_in[12];
  const float* W2 = (const float*)d_in[13];
  const float* bf2v = (const float*)d_in[14];
  float* out = (float*)d_out;

  char* w = (char*)d_ws;
  size_t off = 0;
  auto alloc = [&](size_t bytes) -> void* {
    void* p = w + off;
    off += (bytes + 255) & ~(size_t)255;
    return p;
  };
  u16* xn_perm = (u16*)alloc(16384ull * 512 * 2);
  u16* xn_res = (u16*)alloc(16384ull * 512 * 2);
  u16* qbuf = (u16*)alloc(128ull * 1024 * 64 * 2);
  u16* kbuf = (u16*)alloc(128ull * 1024 * 64 * 2);
  u16* vtb = (u16*)alloc(128ull * 64 * 1024 * 2);
  u16* wqkv_t = (u16*)alloc(1536ull * 512 * 2);
  u16* w1t = (u16*)alloc(1024ull * 512 * 2);
  u16* w2t = (u16*)alloc(512ull * 1024 * 2);
  float* gram = (float*)alloc(2ull * 128 * 8 * 4096 * 4);
  u16* h_bf = (u16*)gram;  // overlay: gram dead before FFN1 writes h
  float* gram2 = (float*)alloc(2ull * 128 * 8 * 64 * 4);
  float* stats = (float*)alloc(128ull * 2 * 4);
  float* ch = (float*)alloc(64ull * 4);
  u16* ao_bf = (u16*)alloc(16384ull * 512 * 2);
  u16* xt_bf = (u16*)alloc(16384ull * 512 * 2);

  k_transpose<<<dim3(8, 8), 256, 0, stream>>>(Wq, wqkv_t, 512, 512);
  k_transpose<<<dim3(8, 8), 256, 0, stream>>>(Wk, wqkv_t + 512 * 512, 512, 512);
  k_transpose<<<dim3(8, 8), 256, 0, stream>>>(Wv, wqkv_t + 1024 * 512, 512, 512);
  k_transpose<<<dim3(16, 8), 256, 0, stream>>>(W1, w1t, 512, 1024);
  k_transpose<<<dim3(8, 16), 256, 0, stream>>>(W2, w2t, 1024, 512);

  k_ln1<<<4096, 256, 0, stream>>>(x, g1, be1, xn_perm, xn_res);

  k_gemm<0><<<dim3(128, 12), 256, 0, stream>>>(xn_perm, wqkv_t, 512, bq, bk, bv,
                                               qbuf, kbuf, vtb, nullptr, nullptr);

  k_gram<<<dim3(8, 128, 2), 256, 0, stream>>>(qbuf, kbuf, gram, gram2);
  k_gram_reduce<<<128, 256, 0, stream>>>(gram, gram2, stats);
  k_scaling<<<1, 64, 0, stream>>>(stats, ch);

  k_attn<<<dim3(128, 8), 256, 0, stream>>>(qbuf, kbuf, vtb, ch, ao_bf);

  k_ln2<<<4096, 256, 0, stream>>>(xn_res, ao_bf, g2, be2, xt_bf);

  k_gemm<1><<<dim3(128, 8), 256, 0, stream>>>(xt_bf, w1t, 512, bf1, nullptr,
                                              nullptr, h_bf, nullptr, nullptr,
                                              nullptr, nullptr);
  k_gemm<2><<<dim3(128, 4), 256, 0, stream>>>(h_bf, w2t, 1024, bf2v, nullptr,
                                              nullptr, nullptr, nullptr, nullptr,
                                              xt_bf, out);
  (void)in_sizes; (void)n_in; (void)out_size; (void)ws_size;
}

// Round 3
// 264.573 us; speedup vs baseline: 1.2242x; 1.2240x over previous
//
#include <hip/hip_runtime.h>
#include <stdint.h>

typedef unsigned short u16;
typedef u16 u16x4 __attribute__((ext_vector_type(4)));
typedef unsigned int u32x4 __attribute__((ext_vector_type(4)));
typedef float f32x4 __attribute__((ext_vector_type(4)));
typedef float f32x16 __attribute__((ext_vector_type(16)));
typedef __bf16 bf16x8 __attribute__((ext_vector_type(8)));

#define DEVI __device__ __forceinline__

DEVI u16 f2bf(float f) {
  uint32_t u = __builtin_bit_cast(uint32_t, f);
  u = (u + 0x7FFFu + ((u >> 16) & 1u)) >> 16;
  return (u16)u;
}
DEVI float bf2f(u16 h) {
  uint32_t u = ((uint32_t)h) << 16;
  return __builtin_bit_cast(float, u);
}
DEVI f32x4 mfma16(u32x4 a, u32x4 b, f32x4 c) {
  return __builtin_amdgcn_mfma_f32_16x16x32_bf16(
      __builtin_bit_cast(bf16x8, a), __builtin_bit_cast(bf16x8, b), c, 0, 0, 0);
}
DEVI f32x16 mfma32(u32x4 a, u32x4 b, f32x16 c) {
  return __builtin_amdgcn_mfma_f32_32x32x16_bf16(
      __builtin_bit_cast(bf16x8, a), __builtin_bit_cast(bf16x8, b), c, 0, 0, 0);
}
DEVI uint32_t cvtpk(float lo, float hi) {
  uint32_t w;
  asm("v_cvt_pk_bf16_f32 %0, %1, %2" : "=v"(w) : "v"(lo), "v"(hi));
  return w;
}
DEVI void plswap(uint32_t& a, uint32_t& b) {
  asm("v_permlane32_swap_b32 %0, %1" : "+v"(a), "+v"(b));
}
DEVI float xmax2(float v) {
  uint32_t a = __builtin_bit_cast(uint32_t, v), b = a;
  plswap(a, b);
  return fmaxf(__builtin_bit_cast(float, a), __builtin_bit_cast(float, b));
}
DEVI float xadd2(float v) {
  uint32_t a = __builtin_bit_cast(uint32_t, v), b = a;
  plswap(a, b);
  return __builtin_bit_cast(float, a) + __builtin_bit_cast(float, b);
}

#define AS1 __attribute__((address_space(1)))
#define AS3 __attribute__((address_space(3)))
DEVI void gload16(const void* g, void* l) {
  __builtin_amdgcn_global_load_lds((AS1 void*)(uintptr_t)g,
                                   (AS3 void*)(uint32_t)(uintptr_t)l, 16, 0, 0);
}

DEVI float wred(float v) {
#pragma unroll
  for (int m = 1; m < 64; m <<= 1) v += __shfl_xor(v, m);
  return v;
}

// ---------------- weight transpose fp32 -> bf16, Wt[N][K] = W[K][N] ----------------
__global__ __launch_bounds__(256) void k_transpose(const float* __restrict__ W,
                                                   u16* __restrict__ Wt, int Kr,
                                                   int Nc) {
  __shared__ float tile[64][65];
  int tid = threadIdx.x;
  int n0 = blockIdx.x * 64, k0 = blockIdx.y * 64;
#pragma unroll
  for (int i = 0; i < 16; i++) {
    int idx = i * 256 + tid;
    int r = idx >> 6, cc = idx & 63;
    tile[r][cc] = W[(size_t)(k0 + r) * Nc + n0 + cc];
  }
  __syncthreads();
#pragma unroll
  for (int i = 0; i < 16; i++) {
    int idx = i * 256 + tid;
    int r = idx >> 6, cc = idx & 63;
    Wt[(size_t)(n0 + r) * Kr + k0 + cc] = f2bf(tile[cc][r]);
  }
}

// ---------------- LN1 ----------------
__global__ __launch_bounds__(256) void k_ln1(const float* __restrict__ x,
                                             const float* __restrict__ gam,
                                             const float* __restrict__ bet,
                                             u16* __restrict__ xn_perm,
                                             u16* __restrict__ xn_res) {
  int tid = threadIdx.x, wid = tid >> 6, lane = tid & 63;
  int row = blockIdx.x * 4 + wid;
  const float* xr = x + (size_t)row * 512 + lane * 8;
  f32x4 v0 = *(const f32x4*)xr;
  f32x4 v1 = *(const f32x4*)(xr + 4);
  float s = 0.f, ss = 0.f;
#pragma unroll
  for (int j = 0; j < 4; j++) {
    s += v0[j] + v1[j];
    ss += v0[j] * v0[j] + v1[j] * v1[j];
  }
  s = wred(s);
  ss = wred(ss);
  float mean = s * (1.0f / 512.0f);
  float var = ss * (1.0f / 512.0f) - mean * mean;
  float rstd = rsqrtf(var + 1e-5f);
  const float* gp = gam + lane * 8;
  const float* bp = bet + lane * 8;
  f32x4 ga = *(const f32x4*)gp, gb = *(const f32x4*)(gp + 4);
  f32x4 ba = *(const f32x4*)bp, bb = *(const f32x4*)(bp + 4);
  u16x4 o0, o1;
#pragma unroll
  for (int j = 0; j < 4; j++) {
    o0[j] = f2bf((v0[j] - mean) * rstd * ga[j] + ba[j]);
    o1[j] = f2bf((v1[j] - mean) * rstd * gb[j] + bb[j]);
  }
  int b = row & 15, a = row >> 4;
  u16* pp = xn_perm + ((size_t)((b << 10) | a)) * 512 + lane * 8;
  *(u16x4*)pp = o0;
  *(u16x4*)(pp + 4) = o1;
  u16* pr = xn_res + (size_t)row * 512 + lane * 8;
  *(u16x4*)pr = o0;
  *(u16x4*)(pr + 4) = o1;
}

// ---------------- LN2 ----------------
__global__ __launch_bounds__(256) void k_ln2(const u16* __restrict__ xn,
                                             const u16* __restrict__ ao,
                                             const float* __restrict__ gam,
                                             const float* __restrict__ bet,
                                             u16* __restrict__ xt) {
  int tid = threadIdx.x, wid = tid >> 6, lane = tid & 63;
  int row = blockIdx.x * 4 + wid;
  size_t base = (size_t)row * 512 + lane * 8;
  u16x4 a0 = *(const u16x4*)&xn[base], a1 = *(const u16x4*)&xn[base + 4];
  u16x4 c0 = *(const u16x4*)&ao[base], c1 = *(const u16x4*)&ao[base + 4];
  float v[8];
#pragma unroll
  for (int j = 0; j < 4; j++) {
    v[j] = bf2f(a0[j]) + bf2f(c0[j]);
    v[4 + j] = bf2f(a1[j]) + bf2f(c1[j]);
  }
  float s = 0.f, ss = 0.f;
#pragma unroll
  for (int j = 0; j < 8; j++) {
    s += v[j];
    ss += v[j] * v[j];
  }
  s = wred(s);
  ss = wred(ss);
  float mean = s * (1.0f / 512.0f);
  float var = ss * (1.0f / 512.0f) - mean * mean;
  float rstd = rsqrtf(var + 1e-5f);
  const float* gp = gam + lane * 8;
  const float* bp = bet + lane * 8;
  u16x4 o0, o1;
#pragma unroll
  for (int j = 0; j < 4; j++) {
    o0[j] = f2bf((v[j] - mean) * rstd * gp[j] + bp[j]);
    o1[j] = f2bf((v[4 + j] - mean) * rstd * gp[4 + j] + bp[4 + j]);
  }
  u16* pr = xt + base;
  *(u16x4*)pr = o0;
  *(u16x4*)(pr + 4) = o1;
}

// ---------------- GEMM C = A * B^T (unchanged) ----------------
template <int EPI>
__global__ __launch_bounds__(256, 2) void k_gemm(
    const u16* __restrict__ A, const u16* __restrict__ B, int K,
    const float* __restrict__ b0, const float* __restrict__ b1,
    const float* __restrict__ b2, u16* __restrict__ o0, u16* __restrict__ o1,
    u16* __restrict__ o2, const u16* __restrict__ resid,
    float* __restrict__ outf) {
  __shared__ __align__(16) u16 As[128 * 64];
  __shared__ __align__(16) u16 Bs[128 * 64];
  const int tid = threadIdx.x;
  const int wid = tid >> 6, lane = tid & 63;
  const int g = lane >> 4, c = lane & 15;
  const int m0 = blockIdx.x * 128, n0 = blockIdx.y * 128;
  const int wr = (wid >> 1) * 64, wc = (wid & 1) * 64;
  const int srow = tid >> 3, scb = tid & 7;

  f32x4 acc[4][4];
  const f32x4 zero = {0.f, 0.f, 0.f, 0.f};
#pragma unroll
  for (int i = 0; i < 4; i++)
#pragma unroll
    for (int j = 0; j < 4; j++) acc[i][j] = zero;

  for (int k0 = 0; k0 < K; k0 += 64) {
    __syncthreads();
#pragma unroll
    for (int i = 0; i < 4; i++) {
      int row = i * 32 + srow;
      int col = ((scb ^ (row & 7)) << 3);
      gload16(A + (size_t)(m0 + row) * K + k0 + col, &As[(i * 256 + tid) * 8]);
      gload16(B + (size_t)(n0 + row) * K + k0 + col, &Bs[(i * 256 + tid) * 8]);
    }
    __syncthreads();
#pragma unroll
    for (int kk = 0; kk < 2; kk++) {
      u32x4 af[4], bfr[4];
#pragma unroll
      for (int mi = 0; mi < 4; mi++) {
        int row = wr + mi * 16 + c;
        int cb = (kk * 4 + g) ^ (row & 7);
        af[mi] = *(const u32x4*)&As[row * 64 + cb * 8];
      }
#pragma unroll
      for (int ni = 0; ni < 4; ni++) {
        int row = wc + ni * 16 + c;
        int cb = (kk * 4 + g) ^ (row & 7);
        bfr[ni] = *(const u32x4*)&Bs[row * 64 + cb * 8];
      }
#pragma unroll
      for (int mi = 0; mi < 4; mi++)
#pragma unroll
        for (int ni = 0; ni < 4; ni++)
          acc[mi][ni] = mfma16(af[mi], bfr[ni], acc[mi][ni]);
    }
  }

  if constexpr (EPI == 0) {
#pragma unroll
    for (int mi = 0; mi < 4; mi++) {
#pragma unroll
      for (int ni = 0; ni < 4; ni++) {
        int n = n0 + wc + ni * 16 + c;
        int which = n >> 9, h = (n >> 6) & 7, dh = n & 63;
        const float* bp = (which == 0) ? b0 : (which == 1) ? b1 : b2;
        float bias = bp[n & 511];
        int mbase = m0 + wr + mi * 16 + g * 4;
        int bb = mbase >> 10, aa = mbase & 1023;
        int bh = bb * 8 + h;
        if (which < 2) {
          u16* dst = ((which == 0) ? o0 : o1) + ((size_t)bh * 1024 + aa) * 64 + dh;
#pragma unroll
          for (int r = 0; r < 4; r++) dst[(size_t)r * 64] = f2bf(acc[mi][ni][r] + bias);
        } else {
          u16x4 pk;
#pragma unroll
          for (int r = 0; r < 4; r++) pk[r] = f2bf(acc[mi][ni][r] + bias);
          *(u16x4*)(o2 + ((size_t)bh * 64 + dh) * 1024 + aa) = pk;
        }
      }
    }
  } else if constexpr (EPI == 1) {
#pragma unroll
    for (int mi = 0; mi < 4; mi++) {
#pragma unroll
      for (int ni = 0; ni < 4; ni++) {
        int n = n0 + wc + ni * 16 + c;
        float bias = b0[n];
#pragma unroll
        for (int r = 0; r < 4; r++) {
          int m = m0 + wr + mi * 16 + g * 4 + r;
          float v = acc[mi][ni][r] + bias;
          v = 0.5f * v * (1.0f + erff(v * 0.70710678118654752f));
          o0[(size_t)m * 1024 + n] = f2bf(v);
        }
      }
    }
  } else {
#pragma unroll
    for (int mi = 0; mi < 4; mi++) {
#pragma unroll
      for (int ni = 0; ni < 4; ni++) {
        int n = n0 + wc + ni * 16 + c;
        float bias = b0[n];
#pragma unroll
        for (int r = 0; r < 4; r++) {
          int m = m0 + wr + mi * 16 + g * 4 + r;
          float v = acc[mi][ni][r] + bias + bf2f(resid[(size_t)m * 512 + n]);
          outf[(size_t)m * 512 + n] = v;
        }
      }
    }
  }
}

// ---------------- Gram partials (unchanged) ----------------
__global__ __launch_bounds__(256) void k_gram(const u16* __restrict__ q,
                                              const u16* __restrict__ k,
                                              float* __restrict__ part,
                                              float* __restrict__ part2) {
  __shared__ float T[128 * 64];
  int tid = threadIdx.x;
  int chunk = blockIdx.x, bh = blockIdx.y, which = blockIdx.z;
  const u16* src = (which == 0 ? q : k) + ((size_t)bh * 1024 + chunk * 128) * 64;
#pragma unroll
  for (int i = 0; i < 8; i++) {
    int e = (i * 256 + tid) * 4;
    u16x4 u = *(const u16x4*)&src[e];
    f32x4 f = {bf2f(u[0]), bf2f(u[1]), bf2f(u[2]), bf2f(u[3])};
    *(f32x4*)&T[e] = f;
  }
  __syncthreads();
  int i0 = (tid >> 4) * 4, j0 = (tid & 15) * 4;
  float accg[4][4] = {};
  for (int a = 0; a < 128; a++) {
    f32x4 qi = *(const f32x4*)&T[a * 64 + i0];
    f32x4 qj = *(const f32x4*)&T[a * 64 + j0];
#pragma unroll
    for (int ii = 0; ii < 4; ii++)
#pragma unroll
      for (int jj = 0; jj < 4; jj++) accg[ii][jj] += qi[ii] * qj[jj];
  }
  float* dst = part + ((((size_t)which * 128 + bh) * 8 + chunk) << 12);
#pragma unroll
  for (int ii = 0; ii < 4; ii++)
#pragma unroll
    for (int jj = 0; jj < 4; jj++) dst[(i0 + ii) * 64 + (j0 + jj)] = accg[ii][jj];
  if (tid < 64) {
    float s = 0.f;
    for (int a = 0; a < 128; a++) s += T[a * 64 + tid];
    part2[(((size_t)which * 128 + bh) * 8 + chunk) * 64 + tid] = s;
  }
}

__global__ __launch_bounds__(256) void k_gram_reduce(const float* __restrict__ part,
                                                     const float* __restrict__ part2,
                                                     float* __restrict__ stats) {
  int bh = blockIdx.x, tid = threadIdx.x;
  const float* pq = part + ((size_t)bh << 15);
  const float* pk = part + ((size_t)(128 + bh) << 15);
  float local = 0.f;
#pragma unroll
  for (int j4 = 0; j4 < 4; j4++) {
    int e = tid * 16 + j4 * 4;
    f32x4 gq = {0.f, 0.f, 0.f, 0.f}, gk = {0.f, 0.f, 0.f, 0.f};
#pragma unroll
    for (int cc = 0; cc < 8; cc++) {
      gq += *(const f32x4*)&pq[cc * 4096 + e];
      gk += *(const f32x4*)&pk[cc * 4096 + e];
    }
    f32x4 p = gq * gk;
    local += p[0] + p[1] + p[2] + p[3];
  }
  local = wred(local);
  __shared__ float red[4];
  if ((tid & 63) == 0) red[tid >> 6] = local;
  __syncthreads();
  float sumv = 0.f;
  if (tid < 64) {
    const float* p2q = part2 + (size_t)bh * 512;
    const float* p2k = part2 + (size_t)(128 + bh) * 512;
    float sq = 0.f, sk = 0.f;
#pragma unroll
    for (int cc = 0; cc < 8; cc++) {
      sq += p2q[cc * 64 + tid];
      sk += p2k[cc * 64 + tid];
    }
    sumv = wred(sq * sk);
  }
  if (tid == 0) {
    stats[bh * 2] = red[0] + red[1] + red[2] + red[3];
    stats[bh * 2 + 1] = sumv;
  }
}

__global__ void k_scaling(const float* __restrict__ stats, float* __restrict__ ch) {
  int h = threadIdx.x;
  if (h < 8) {
    float ssq = 0.f, sm = 0.f;
    for (int b = 0; b < 16; b++) {
      ssq += stats[(b * 8 + h) * 2];
      sm += stats[(b * 8 + h) * 2 + 1];
    }
    const float N = 16777216.0f;
    float var = (ssq - sm * sm / N) / (N - 1.0f);
    float sd = sqrtf(fmaxf(var, 0.0f));
    float scal = 8.0f * sqrtf(1.0f + sd);
    ch[h] = 1.4426950408889634f / scal;  // log2(e)/scaling
  }
}

// ---------------- flash attention: LDS-staged K/V + in-register swapped softmax --------
// Block: 4 waves, one (bh, 128-q tile). K/V 64-kv tiles double-buffered in LDS
// (coalesced global_load_lds, source-side XOR swizzle); softmax fully in-lane
// via swapped-operand mfma32 (S^T = K*Q^T, O^T = V^T*P^T).
__global__ __launch_bounds__(256) void k_attn(const u16* __restrict__ q,
                                              const u16* __restrict__ k,
                                              const u16* __restrict__ vt,
                                              const float* __restrict__ ch_arr,
                                              u16* __restrict__ ao) {
  __shared__ __align__(16) u16 Ks[2][64 * 64];
  __shared__ __align__(16) u16 Vs[2][64 * 64];
  int tid = threadIdx.x, wid = tid >> 6, lane = tid & 63;
  int r = lane & 31, hi = lane >> 5, h8 = hi * 8;
  int bh = blockIdx.x, qt = blockIdx.y;  // bh on x -> all q-tiles of a bh on one XCD
  int b = bh >> 3, h = bh & 7;
  float sc = ch_arr[h];
  int q0 = qt * 128 + wid * 32;
  const u16* qb = q + ((size_t)bh << 16);
  const u16* kb = k + ((size_t)bh << 16);
  const u16* vb = vt + ((size_t)bh << 16);
  const int srow = tid >> 3, scb = tid & 7;

  // Q fragments, scaled by log2(e)/scaling, repacked to bf16
  u32x4 qf[4];
  const u16* qrow = qb + (size_t)(q0 + r) * 64 + h8;
#pragma unroll
  for (int ks = 0; ks < 4; ks++) {
    u32x4 raw = *(const u32x4*)(qrow + ks * 16);
    u32x4 w;
#pragma unroll
    for (int t = 0; t < 4; t++) {
      float lo = bf2f((u16)(raw[t] & 0xffffu)) * sc;
      float hi_ = bf2f((u16)(raw[t] >> 16)) * sc;
      w[t] = cvtpk(lo, hi_);
    }
    qf[ks] = w;
  }

  f32x16 o0 = {0.f, 0.f, 0.f, 0.f, 0.f, 0.f, 0.f, 0.f,
               0.f, 0.f, 0.f, 0.f, 0.f, 0.f, 0.f, 0.f};
  f32x16 o1 = o0;
  float m_run = -1e30f, l_run = 0.f;

  auto stage = [&](int buf, int t0) {
#pragma unroll
    for (int i = 0; i < 2; i++) {
      int row = i * 32 + srow;                 // local row (kv for K, dh for V)
      int col = ((scb ^ (row & 7)) << 3);      // source-side swizzle
      gload16(kb + (size_t)(t0 + row) * 64 + col, &Ks[buf][(i * 256 + tid) * 8]);
      gload16(vb + (size_t)row * 1024 + t0 + col, &Vs[buf][(i * 256 + tid) * 8]);
    }
  };

  stage(0, 0);
  int cur = 0;
  for (int t0 = 0; t0 < 1024; t0 += 64) {
    __syncthreads();  // drains vmcnt(0): buf[cur] staged; prev readers done
    if (t0 + 64 < 1024) stage(cur ^ 1, t0 + 64);
    const u16* Kc = Ks[cur];
    const u16* Vc = Vs[cur];
#pragma unroll
    for (int ss = 0; ss < 2; ss++) {
      // K fragments (rows = kv), QK^T
      f32x16 st = {0.f, 0.f, 0.f, 0.f, 0.f, 0.f, 0.f, 0.f,
                   0.f, 0.f, 0.f, 0.f, 0.f, 0.f, 0.f, 0.f};
      int rk = ss * 32 + r;
#pragma unroll
      for (int ks = 0; ks < 4; ks++) {
        int cb = (ks * 2 + hi) ^ (rk & 7);
        u32x4 kf = *(const u32x4*)&Kc[rk * 64 + cb * 8];
        st = mfma32(kf, qf[ks], st);
      }
      // in-lane softmax (q = lane&31 owns its row slice)
      float mx[8];
#pragma unroll
      for (int i = 0; i < 8; i++) mx[i] = fmaxf(st[i], st[i + 8]);
#pragma unroll
      for (int i = 0; i < 4; i++) mx[i] = fmaxf(mx[i], mx[i + 4]);
      float pm = fmaxf(fmaxf(mx[0], mx[2]), fmaxf(mx[1], mx[3]));
      pm = xmax2(pm);
      if (__any(pm > m_run + 8.0f)) {  // defer-max (T13)
        float mnew = fmaxf(m_run, pm);
        float al = exp2f(m_run - mnew);
        l_run *= al;
#pragma unroll
        for (int i = 0; i < 16; i++) {
          o0[i] *= al;
          o1[i] *= al;
        }
        m_run = mnew;
      }
      float p[16];
#pragma unroll
      for (int i = 0; i < 16; i++) p[i] = exp2f(st[i] - m_run);
      float sm[8];
#pragma unroll
      for (int i = 0; i < 8; i++) sm[i] = p[i] + p[i + 8];
#pragma unroll
      for (int i = 0; i < 4; i++) sm[i] += sm[i + 4];
      float rs = (sm[0] + sm[2]) + (sm[1] + sm[3]);
      l_run += xadd2(rs);
      // P^T -> bf16 fragments, PV
#pragma unroll
      for (int ks = 0; ks < 2; ks++) {
        uint32_t A0 = cvtpk(p[ks * 8 + 0], p[ks * 8 + 1]);
        uint32_t A1 = cvtpk(p[ks * 8 + 4], p[ks * 8 + 5]);
        plswap(A0, A1);
        uint32_t B0 = cvtpk(p[ks * 8 + 2], p[ks * 8 + 3]);
        uint32_t B1 = cvtpk(p[ks * 8 + 6], p[ks * 8 + 7]);
        plswap(B0, B1);
        u32x4 pa = {A0, B0, A1, B1};
        // V fragments: rows = dh, K-dim = kv (chunk c = ss*4 + ks*2 + hi)
#pragma unroll
        for (int mt = 0; mt < 2; mt++) {
          int rv = mt * 32 + r;
          int cb = (ss * 4 + ks * 2 + hi) ^ (rv & 7);
          u32x4 vf = *(const u32x4*)&Vc[rv * 64 + cb * 8];
          if (mt == 0)
            o0 = mfma32(vf, pa, o0);
          else
            o1 = mfma32(vf, pa, o1);
        }
      }
    }
    cur ^= 1;
  }

  float inv = 1.0f / l_run;
  int a_idx = q0 + r;
  u16* aop = ao + ((size_t)(a_idx * 16 + b)) * 512 + h * 64;
#pragma unroll
  for (int i = 0; i < 16; i++) {
    int dh0 = (i & 3) + 8 * (i >> 2) + 4 * hi;
    aop[dh0] = f2bf(o0[i] * inv);
    aop[32 + dh0] = f2bf(o1[i] * inv);
  }
}

extern "C" void kernel_launch(void* const* d_in, const int* in_sizes, int n_in,
                              void* d_out, int out_size, void* d_ws, size_t ws_size,
                              hipStream_t stream) {
  const float* x = (const float*)d_in[0];
  const float* Wq = (const float*)d_in[1];
  const float* bq = (const float*)d_in[2];
  const float* Wk = (const float*)d_in[3];
  const float* bk = (const float*)d_in[4];
  const float* Wv = (const float*)d_in[5];
  const float* bv = (const float*)d_in[6];
  const float* g1 = (const float*)d_in[7];
  const float* be1 = (const float*)d_in[8];
  const float* g2 = (const float*)d_in[9];
  const float* be2 = (const float*)d_in[10];
  const float* W1 = (const float*)d_in[11];
  const float* bf1 = (const float*)d_in[12];
  const float* W2 = (const float*)d_in[13];
  const float* bf2v = (const float*)d_in[14];
  float* out = (float*)d_out;

  char* w = (char*)d_ws;
  size_t off = 0;
  auto alloc = [&](size_t bytes) -> void* {
    void* p = w + off;
    off += (bytes + 255) & ~(size_t)255;
    return p;
  };
  u16* xn_perm = (u16*)alloc(16384ull * 512 * 2);
  u16* xn_res = (u16*)alloc(16384ull * 512 * 2);
  u16* qbuf = (u16*)alloc(128ull * 1024 * 64 * 2);
  u16* kbuf = (u16*)alloc(128ull * 1024 * 64 * 2);
  u16* vtb = (u16*)alloc(128ull * 64 * 1024 * 2);
  u16* wqkv_t = (u16*)alloc(1536ull * 512 * 2);
  u16* w1t = (u16*)alloc(1024ull * 512 * 2);
  u16* w2t = (u16*)alloc(512ull * 1024 * 2);
  float* gram = (float*)alloc(2ull * 128 * 8 * 4096 * 4);
  u16* h_bf = (u16*)gram;  // overlay: gram dead before FFN1 writes h
  float* gram2 = (float*)alloc(2ull * 128 * 8 * 64 * 4);
  float* stats = (float*)alloc(128ull * 2 * 4);
  float* ch = (float*)alloc(64ull * 4);
  u16* ao_bf = (u16*)alloc(16384ull * 512 * 2);
  u16* xt_bf = (u16*)alloc(16384ull * 512 * 2);

  k_transpose<<<dim3(8, 8), 256, 0, stream>>>(Wq, wqkv_t, 512, 512);
  k_transpose<<<dim3(8, 8), 256, 0, stream>>>(Wk, wqkv_t + 512 * 512, 512, 512);
  k_transpose<<<dim3(8, 8), 256, 0, stream>>>(Wv, wqkv_t + 1024 * 512, 512, 512);
  k_transpose<<<dim3(16, 8), 256, 0, stream>>>(W1, w1t, 512, 1024);
  k_transpose<<<dim3(8, 16), 256, 0, stream>>>(W2, w2t, 1024, 512);

  k_ln1<<<4096, 256, 0, stream>>>(x, g1, be1, xn_perm, xn_res);

  k_gemm<0><<<dim3(128, 12), 256, 0, stream>>>(xn_perm, wqkv_t, 512, bq, bk, bv,
                                               qbuf, kbuf, vtb, nullptr, nullptr);

  k_gram<<<dim3(8, 128, 2), 256, 0, stream>>>(qbuf, kbuf, gram, gram2);
  k_gram_reduce<<<128, 256, 0, stream>>>(gram, gram2, stats);
  k_scaling<<<1, 64, 0, stream>>>(stats, ch);

  k_attn<<<dim3(128, 8), 256, 0, stream>>>(qbuf, kbuf, vtb, ch, ao_bf);

  k_ln2<<<4096, 256, 0, stream>>>(xn_res, ao_bf, g2, be2, xt_bf);

  k_gemm<1><<<dim3(128, 8), 256, 0, stream>>>(xt_bf, w1t, 512, bf1, nullptr,
                                              nullptr, h_bf, nullptr, nullptr,
                                              nullptr, nullptr);
  k_gemm<2><<<dim3(128, 4), 256, 0, stream>>>(h_bf, w2t, 1024, bf2v, nullptr,
                                              nullptr, nullptr, nullptr, nullptr,
                                              xt_bf, out);
  (void)in_sizes; (void)n_in; (void)out_size; (void)ws_size;
}

// Round 5
// 260.202 us; speedup vs baseline: 1.2448x; 1.0168x over previous
//
#include <hip/hip_runtime.h>
#include <stdint.h>

typedef unsigned short u16;
typedef u16 u16x4 __attribute__((ext_vector_type(4)));
typedef unsigned int u32x4 __attribute__((ext_vector_type(4)));
typedef float f32x4 __attribute__((ext_vector_type(4)));
typedef float f32x16 __attribute__((ext_vector_type(16)));
typedef __bf16 bf16x8 __attribute__((ext_vector_type(8)));

#define DEVI __device__ __forceinline__

DEVI u16 f2bf(float f) {
  uint32_t u = __builtin_bit_cast(uint32_t, f);
  u = (u + 0x7FFFu + ((u >> 16) & 1u)) >> 16;
  return (u16)u;
}
DEVI float bf2f(u16 h) {
  uint32_t u = ((uint32_t)h) << 16;
  return __builtin_bit_cast(float, u);
}
DEVI f32x4 mfma16(u32x4 a, u32x4 b, f32x4 c) {
  return __builtin_amdgcn_mfma_f32_16x16x32_bf16(
      __builtin_bit_cast(bf16x8, a), __builtin_bit_cast(bf16x8, b), c, 0, 0, 0);
}
DEVI f32x16 mfma32(u32x4 a, u32x4 b, f32x16 c) {
  return __builtin_amdgcn_mfma_f32_32x32x16_bf16(
      __builtin_bit_cast(bf16x8, a), __builtin_bit_cast(bf16x8, b), c, 0, 0, 0);
}
DEVI uint32_t cvtpk(float lo, float hi) {
  uint32_t w;
  asm("v_cvt_pk_bf16_f32 %0, %1, %2" : "=v"(w) : "v"(lo), "v"(hi));
  return w;
}
DEVI void plswap(uint32_t& a, uint32_t& b) {
  asm("v_permlane32_swap_b32 %0, %1" : "+v"(a), "+v"(b));
}
DEVI float xmax2(float v) {
  uint32_t a = __builtin_bit_cast(uint32_t, v), b = a;
  plswap(a, b);
  return fmaxf(__builtin_bit_cast(float, a), __builtin_bit_cast(float, b));
}

#define AS1 __attribute__((address_space(1)))
#define AS3 __attribute__((address_space(3)))
DEVI void gload16(const void* g, void* l) {
  __builtin_amdgcn_global_load_lds((AS1 void*)(uintptr_t)g,
                                   (AS3 void*)(uint32_t)(uintptr_t)l, 16, 0, 0);
}

DEVI float wred(float v) {
#pragma unroll
  for (int m = 1; m < 64; m <<= 1) v += __shfl_xor(v, m);
  return v;
}

// ---------------- weight transpose fp32 -> bf16, Wt[N][K] = W[K][N] ----------------
__global__ __launch_bounds__(256) void k_transpose(const float* __restrict__ W,
                                                   u16* __restrict__ Wt, int Kr,
                                                   int Nc) {
  __shared__ float tile[64][65];
  int tid = threadIdx.x;
  int n0 = blockIdx.x * 64, k0 = blockIdx.y * 64;
#pragma unroll
  for (int i = 0; i < 16; i++) {
    int idx = i * 256 + tid;
    int r = idx >> 6, cc = idx & 63;
    tile[r][cc] = W[(size_t)(k0 + r) * Nc + n0 + cc];
  }
  __syncthreads();
#pragma unroll
  for (int i = 0; i < 16; i++) {
    int idx = i * 256 + tid;
    int r = idx >> 6, cc = idx & 63;
    Wt[(size_t)(n0 + r) * Kr + k0 + cc] = f2bf(tile[cc][r]);
  }
}

// ---------------- LN1 ----------------
__global__ __launch_bounds__(256) void k_ln1(const float* __restrict__ x,
                                             const float* __restrict__ gam,
                                             const float* __restrict__ bet,
                                             u16* __restrict__ xn_perm,
                                             u16* __restrict__ xn_res) {
  int tid = threadIdx.x, wid = tid >> 6, lane = tid & 63;
  int row = blockIdx.x * 4 + wid;
  const float* xr = x + (size_t)row * 512 + lane * 8;
  f32x4 v0 = *(const f32x4*)xr;
  f32x4 v1 = *(const f32x4*)(xr + 4);
  float s = 0.f, ss = 0.f;
#pragma unroll
  for (int j = 0; j < 4; j++) {
    s += v0[j] + v1[j];
    ss += v0[j] * v0[j] + v1[j] * v1[j];
  }
  s = wred(s);
  ss = wred(ss);
  float mean = s * (1.0f / 512.0f);
  float var = ss * (1.0f / 512.0f) - mean * mean;
  float rstd = rsqrtf(var + 1e-5f);
  const float* gp = gam + lane * 8;
  const float* bp = bet + lane * 8;
  f32x4 ga = *(const f32x4*)gp, gb = *(const f32x4*)(gp + 4);
  f32x4 ba = *(const f32x4*)bp, bb = *(const f32x4*)(bp + 4);
  u16x4 o0, o1;
#pragma unroll
  for (int j = 0; j < 4; j++) {
    o0[j] = f2bf((v0[j] - mean) * rstd * ga[j] + ba[j]);
    o1[j] = f2bf((v1[j] - mean) * rstd * gb[j] + bb[j]);
  }
  int b = row & 15, a = row >> 4;
  u16* pp = xn_perm + ((size_t)((b << 10) | a)) * 512 + lane * 8;
  *(u16x4*)pp = o0;
  *(u16x4*)(pp + 4) = o1;
  u16* pr = xn_res + (size_t)row * 512 + lane * 8;
  *(u16x4*)pr = o0;
  *(u16x4*)(pr + 4) = o1;
}

// ---------------- LN2 ----------------
__global__ __launch_bounds__(256) void k_ln2(const u16* __restrict__ xn,
                                             const u16* __restrict__ ao,
                                             const float* __restrict__ gam,
                                             const float* __restrict__ bet,
                                             u16* __restrict__ xt) {
  int tid = threadIdx.x, wid = tid >> 6, lane = tid & 63;
  int row = blockIdx.x * 4 + wid;
  size_t base = (size_t)row * 512 + lane * 8;
  u16x4 a0 = *(const u16x4*)&xn[base], a1 = *(const u16x4*)&xn[base + 4];
  u16x4 c0 = *(const u16x4*)&ao[base], c1 = *(const u16x4*)&ao[base + 4];
  float v[8];
#pragma unroll
  for (int j = 0; j < 4; j++) {
    v[j] = bf2f(a0[j]) + bf2f(c0[j]);
    v[4 + j] = bf2f(a1[j]) + bf2f(c1[j]);
  }
  float s = 0.f, ss = 0.f;
#pragma unroll
  for (int j = 0; j < 8; j++) {
    s += v[j];
    ss += v[j] * v[j];
  }
  s = wred(s);
  ss = wred(ss);
  float mean = s * (1.0f / 512.0f);
  float var = ss * (1.0f / 512.0f) - mean * mean;
  float rstd = rsqrtf(var + 1e-5f);
  const float* gp = gam + lane * 8;
  const float* bp = bet + lane * 8;
  u16x4 o0, o1;
#pragma unroll
  for (int j = 0; j < 4; j++) {
    o0[j] = f2bf((v[j] - mean) * rstd * gp[j] + bp[j]);
    o1[j] = f2bf((v[4 + j] - mean) * rstd * gp[4 + j] + bp[4 + j]);
  }
  u16* pr = xt + base;
  *(u16x4*)pr = o0;
  *(u16x4*)(pr + 4) = o1;
}

// ---------------- GEMM C = A * B^T, BM x 128 tile, BK=64 ----------------
template <int EPI, int BM>
__global__ __launch_bounds__(256, 2) void k_gemm(
    const u16* __restrict__ A, const u16* __restrict__ B, int K,
    const float* __restrict__ b0, const float* __restrict__ b1,
    const float* __restrict__ b2, u16* __restrict__ o0, u16* __restrict__ o1,
    u16* __restrict__ o2, const u16* __restrict__ resid,
    float* __restrict__ outf) {
  constexpr int MI = BM / 32;  // acc rows per wave (of 16)
  __shared__ __align__(16) u16 As[BM * 64];
  __shared__ __align__(16) u16 Bs[128 * 64];
  const int tid = threadIdx.x;
  const int wid = tid >> 6, lane = tid & 63;
  const int g = lane >> 4, c = lane & 15;
  const int m0 = blockIdx.x * BM, n0 = blockIdx.y * 128;
  const int wr = (wid >> 1) * (BM / 2), wc = (wid & 1) * 64;
  const int srow = tid >> 3, scb = tid & 7;

  f32x4 acc[MI][4];
  const f32x4 zero = {0.f, 0.f, 0.f, 0.f};
#pragma unroll
  for (int i = 0; i < MI; i++)
#pragma unroll
    for (int j = 0; j < 4; j++) acc[i][j] = zero;

  for (int k0 = 0; k0 < K; k0 += 64) {
    __syncthreads();
#pragma unroll
    for (int i = 0; i < BM / 32; i++) {
      int row = i * 32 + srow;
      int col = ((scb ^ (row & 7)) << 3);
      gload16(A + (size_t)(m0 + row) * K + k0 + col, &As[(i * 256 + tid) * 8]);
    }
#pragma unroll
    for (int i = 0; i < 4; i++) {
      int row = i * 32 + srow;
      int col = ((scb ^ (row & 7)) << 3);
      gload16(B + (size_t)(n0 + row) * K + k0 + col, &Bs[(i * 256 + tid) * 8]);
    }
    __syncthreads();
#pragma unroll
    for (int kk = 0; kk < 2; kk++) {
      u32x4 af[MI], bfr[4];
#pragma unroll
      for (int mi = 0; mi < MI; mi++) {
        int row = wr + mi * 16 + c;
        int cb = (kk * 4 + g) ^ (row & 7);
        af[mi] = *(const u32x4*)&As[row * 64 + cb * 8];
      }
#pragma unroll
      for (int ni = 0; ni < 4; ni++) {
        int row = wc + ni * 16 + c;
        int cb = (kk * 4 + g) ^ (row & 7);
        bfr[ni] = *(const u32x4*)&Bs[row * 64 + cb * 8];
      }
#pragma unroll
      for (int mi = 0; mi < MI; mi++)
#pragma unroll
        for (int ni = 0; ni < 4; ni++)
          acc[mi][ni] = mfma16(af[mi], bfr[ni], acc[mi][ni]);
    }
  }

  if constexpr (EPI == 0) {
#pragma unroll
    for (int mi = 0; mi < MI; mi++) {
#pragma unroll
      for (int ni = 0; ni < 4; ni++) {
        int n = n0 + wc + ni * 16 + c;
        int which = n >> 9, h = (n >> 6) & 7, dh = n & 63;
        const float* bp = (which == 0) ? b0 : (which == 1) ? b1 : b2;
        float bias = bp[n & 511];
        int mbase = m0 + wr + mi * 16 + g * 4;
        int bb = mbase >> 10, aa = mbase & 1023;
        int bh = bb * 8 + h;
        if (which < 2) {
          u16* dst = ((which == 0) ? o0 : o1) + ((size_t)bh * 1024 + aa) * 64 + dh;
#pragma unroll
          for (int r = 0; r < 4; r++) dst[(size_t)r * 64] = f2bf(acc[mi][ni][r] + bias);
        } else {
          u16x4 pk;
#pragma unroll
          for (int r = 0; r < 4; r++) pk[r] = f2bf(acc[mi][ni][r] + bias);
          *(u16x4*)(o2 + ((size_t)bh * 64 + dh) * 1024 + aa) = pk;
        }
      }
    }
  } else if constexpr (EPI == 1) {
#pragma unroll
    for (int mi = 0; mi < MI; mi++) {
#pragma unroll
      for (int ni = 0; ni < 4; ni++) {
        int n = n0 + wc + ni * 16 + c;
        float bias = b0[n];
#pragma unroll
        for (int r = 0; r < 4; r++) {
          int m = m0 + wr + mi * 16 + g * 4 + r;
          float v = acc[mi][ni][r] + bias;
          v = 0.5f * v * (1.0f + erff(v * 0.70710678118654752f));
          o0[(size_t)m * 1024 + n] = f2bf(v);
        }
      }
    }
  } else {
#pragma unroll
    for (int mi = 0; mi < MI; mi++) {
#pragma unroll
      for (int ni = 0; ni < 4; ni++) {
        int n = n0 + wc + ni * 16 + c;
        float bias = b0[n];
#pragma unroll
        for (int r = 0; r < 4; r++) {
          int m = m0 + wr + mi * 16 + g * 4 + r;
          float v = acc[mi][ni][r] + bias + bf2f(resid[(size_t)m * 512 + n]);
          outf[(size_t)m * 512 + n] = v;
        }
      }
    }
  }
}

// ---------------- Gram partials ----------------
__global__ __launch_bounds__(256) void k_gram(const u16* __restrict__ q,
                                              const u16* __restrict__ k,
                                              float* __restrict__ part,
                                              float* __restrict__ part2) {
  __shared__ float T[128 * 64];
  int tid = threadIdx.x;
  int chunk = blockIdx.x, bh = blockIdx.y, which = blockIdx.z;
  const u16* src = (which == 0 ? q : k) + ((size_t)bh * 1024 + chunk * 128) * 64;
#pragma unroll
  for (int i = 0; i < 8; i++) {
    int e = (i * 256 + tid) * 4;
    u16x4 u = *(const u16x4*)&src[e];
    f32x4 f = {bf2f(u[0]), bf2f(u[1]), bf2f(u[2]), bf2f(u[3])};
    *(f32x4*)&T[e] = f;
  }
  __syncthreads();
  int i0 = (tid >> 4) * 4, j0 = (tid & 15) * 4;
  float accg[4][4] = {};
  for (int a = 0; a < 128; a++) {
    f32x4 qi = *(const f32x4*)&T[a * 64 + i0];
    f32x4 qj = *(const f32x4*)&T[a * 64 + j0];
#pragma unroll
    for (int ii = 0; ii < 4; ii++)
#pragma unroll
      for (int jj = 0; jj < 4; jj++) accg[ii][jj] += qi[ii] * qj[jj];
  }
  float* dst = part + ((((size_t)which * 128 + bh) * 8 + chunk) << 12);
#pragma unroll
  for (int ii = 0; ii < 4; ii++)
#pragma unroll
    for (int jj = 0; jj < 4; jj++) dst[(i0 + ii) * 64 + (j0 + jj)] = accg[ii][jj];
  if (tid < 64) {
    float s = 0.f;
    for (int a = 0; a < 128; a++) s += T[a * 64 + tid];
    part2[(((size_t)which * 128 + bh) * 8 + chunk) * 64 + tid] = s;
  }
}

__global__ __launch_bounds__(256) void k_gram_reduce(const float* __restrict__ part,
                                                     const float* __restrict__ part2,
                                                     float* __restrict__ stats) {
  int bh = blockIdx.x, tid = threadIdx.x;
  const float* pq = part + ((size_t)bh << 15);
  const float* pk = part + ((size_t)(128 + bh) << 15);
  float local = 0.f;
#pragma unroll
  for (int j4 = 0; j4 < 4; j4++) {
    int e = tid * 16 + j4 * 4;
    f32x4 gq = {0.f, 0.f, 0.f, 0.f}, gk = {0.f, 0.f, 0.f, 0.f};
#pragma unroll
    for (int cc = 0; cc < 8; cc++) {
      gq += *(const f32x4*)&pq[cc * 4096 + e];
      gk += *(const f32x4*)&pk[cc * 4096 + e];
    }
    f32x4 p = gq * gk;
    local += p[0] + p[1] + p[2] + p[3];
  }
  local = wred(local);
  __shared__ float red[4];
  if ((tid & 63) == 0) red[tid >> 6] = local;
  __syncthreads();
  float sumv = 0.f;
  if (tid < 64) {
    const float* p2q = part2 + (size_t)bh * 512;
    const float* p2k = part2 + (size_t)(128 + bh) * 512;
    float sq = 0.f, sk = 0.f;
#pragma unroll
    for (int cc = 0; cc < 8; cc++) {
      sq += p2q[cc * 64 + tid];
      sk += p2k[cc * 64 + tid];
    }
    sumv = wred(sq * sk);
  }
  if (tid == 0) {
    stats[bh * 2] = red[0] + red[1] + red[2] + red[3];
    stats[bh * 2 + 1] = sumv;
  }
}

__global__ void k_scaling(const float* __restrict__ stats, float* __restrict__ ch) {
  int h = threadIdx.x;
  if (h < 8) {
    float ssq = 0.f, sm = 0.f;
    for (int b = 0; b < 16; b++) {
      ssq += stats[(b * 8 + h) * 2];
      sm += stats[(b * 8 + h) * 2 + 1];
    }
    const float N = 16777216.0f;
    float var = (ssq - sm * sm / N) / (N - 1.0f);
    float sd = sqrtf(fmaxf(var, 0.0f));
    float scal = 8.0f * sqrtf(1.0f + sd);
    ch[h] = 1.4426950408889634f / scal;  // log2(e)/scaling
  }
}

// ---------------- flash attention: LDS-staged K/V, in-lane defer-max softmax --------
// P numerics identical to the validated R3 kernel (defer-max, THR=8). Row-sum l is
// computed on the MFMA pipe via mfma32(ones, P): every output reg of lacc equals
// sum_k P[k][q], so l = lacc[0] with zero VALU tree. l thus uses the same
// bf16-rounded P as the numerator (consistent convex weights).
__global__ __launch_bounds__(256, 3) void k_attn(const u16* __restrict__ q,
                                                 const u16* __restrict__ k,
                                                 const u16* __restrict__ vt,
                                                 const float* __restrict__ ch_arr,
                                                 u16* __restrict__ ao) {
  __shared__ __align__(16) u16 Ks[2][64 * 64];
  __shared__ __align__(16) u16 Vs[2][64 * 64];
  int tid = threadIdx.x, wid = tid >> 6, lane = tid & 63;
  int r = lane & 31, hi = lane >> 5, h8 = hi * 8;
  int bh = blockIdx.x, qt = blockIdx.y;
  int b = bh >> 3, h = bh & 7;
  float sc = ch_arr[h];
  int q0 = qt * 128 + wid * 32;
  const u16* qb = q + ((size_t)bh << 16);
  const u16* kb = k + ((size_t)bh << 16);
  const u16* vb = vt + ((size_t)bh << 16);
  const int srow = tid >> 3, scb = tid & 7;
  const u32x4 ones = {0x3F803F80u, 0x3F803F80u, 0x3F803F80u, 0x3F803F80u};

  // Q fragments, scaled by log2(e)/scaling, repacked to bf16
  u32x4 qf[4];
  const u16* qrow = qb + (size_t)(q0 + r) * 64 + h8;
#pragma unroll
  for (int ks = 0; ks < 4; ks++) {
    u32x4 raw = *(const u32x4*)(qrow + ks * 16);
    u32x4 w;
#pragma unroll
    for (int t = 0; t < 4; t++) {
      float lo = bf2f((u16)(raw[t] & 0xffffu)) * sc;
      float hi_ = bf2f((u16)(raw[t] >> 16)) * sc;
      w[t] = cvtpk(lo, hi_);
    }
    qf[ks] = w;
  }

  const f32x16 zero16 = {0.f, 0.f, 0.f, 0.f, 0.f, 0.f, 0.f, 0.f,
                         0.f, 0.f, 0.f, 0.f, 0.f, 0.f, 0.f, 0.f};
  f32x16 o0 = zero16, o1 = zero16, lacc = zero16;
  float m_run = -1e30f;

  auto stage = [&](int buf, int t0) {
#pragma unroll
    for (int i = 0; i < 2; i++) {
      int row = i * 32 + srow;
      int col = ((scb ^ (row & 7)) << 3);
      gload16(kb + (size_t)(t0 + row) * 64 + col, &Ks[buf][(i * 256 + tid) * 8]);
      gload16(vb + (size_t)row * 1024 + t0 + col, &Vs[buf][(i * 256 + tid) * 8]);
    }
  };

  stage(0, 0);
  int cur = 0;
  for (int t0 = 0; t0 < 1024; t0 += 64) {
    __syncthreads();  // drains vmcnt(0): buf[cur] staged; prev readers done
    if (t0 + 64 < 1024) stage(cur ^ 1, t0 + 64);
    const u16* Kc = Ks[cur];
    const u16* Vc = Vs[cur];
#pragma unroll
    for (int ss = 0; ss < 2; ss++) {
      f32x16 st = zero16;
      int rk = ss * 32 + r;
      __builtin_amdgcn_s_setprio(1);
#pragma unroll
      for (int ks = 0; ks < 4; ks++) {
        int cb = (ks * 2 + hi) ^ (rk & 7);
        u32x4 kf = *(const u32x4*)&Kc[rk * 64 + cb * 8];
        st = mfma32(kf, qf[ks], st);
      }
      __builtin_amdgcn_s_setprio(0);
      // tile max (in-lane tree + cross-half swap), defer-max THR=8
      float mx[8];
#pragma unroll
      for (int i = 0; i < 8; i++) mx[i] = fmaxf(st[i], st[i + 8]);
#pragma unroll
      for (int i = 0; i < 4; i++) mx[i] = fmaxf(mx[i], mx[i + 4]);
      float pm = fmaxf(fmaxf(mx[0], mx[2]), fmaxf(mx[1], mx[3]));
      pm = xmax2(pm);
      if (__any(pm > m_run + 8.0f)) {
        float mnew = fmaxf(m_run, pm);
        float al = exp2f(m_run - mnew);
        lacc[0] *= al;
#pragma unroll
        for (int i = 0; i < 16; i++) {
          o0[i] *= al;
          o1[i] *= al;
        }
        m_run = mnew;
      }
      float p[16];
#pragma unroll
      for (int i = 0; i < 16; i++) p[i] = exp2f(st[i] - m_run);
      // P^T -> bf16 fragments; PV + ones-row l on the MFMA pipe
      __builtin_amdgcn_s_setprio(1);
#pragma unroll
      for (int ks = 0; ks < 2; ks++) {
        uint32_t A0 = cvtpk(p[ks * 8 + 0], p[ks * 8 + 1]);
        uint32_t A1 = cvtpk(p[ks * 8 + 4], p[ks * 8 + 5]);
        plswap(A0, A1);
        uint32_t B0 = cvtpk(p[ks * 8 + 2], p[ks * 8 + 3]);
        uint32_t B1 = cvtpk(p[ks * 8 + 6], p[ks * 8 + 7]);
        plswap(B0, B1);
        u32x4 pa = {A0, B0, A1, B1};
        lacc = mfma32(ones, pa, lacc);
#pragma unroll
        for (int mt = 0; mt < 2; mt++) {
          int rv = mt * 32 + r;
          int cb = (ss * 4 + ks * 2 + hi) ^ (rv & 7);
          u32x4 vf = *(const u32x4*)&Vc[rv * 64 + cb * 8];
          if (mt == 0)
            o0 = mfma32(vf, pa, o0);
          else
            o1 = mfma32(vf, pa, o1);
        }
      }
      __builtin_amdgcn_s_setprio(0);
    }
    cur ^= 1;
  }

  float inv = 1.0f / lacc[0];
  int a_idx = q0 + r;
  u16* aop = ao + ((size_t)(a_idx * 16 + b)) * 512 + h * 64;
#pragma unroll
  for (int i = 0; i < 16; i++) {
    int dh0 = (i & 3) + 8 * (i >> 2) + 4 * hi;
    aop[dh0] = f2bf(o0[i] * inv);
    aop[32 + dh0] = f2bf(o1[i] * inv);
  }
}

extern "C" void kernel_launch(void* const* d_in, const int* in_sizes, int n_in,
                              void* d_out, int out_size, void* d_ws, size_t ws_size,
                              hipStream_t stream) {
  const float* x = (const float*)d_in[0];
  const float* Wq = (const float*)d_in[1];
  const float* bq = (const float*)d_in[2];
  const float* Wk = (const float*)d_in[3];
  const float* bk = (const float*)d_in[4];
  const float* Wv = (const float*)d_in[5];
  const float* bv = (const float*)d_in[6];
  const float* g1 = (const float*)d_in[7];
  const float* be1 = (const float*)d_in[8];
  const float* g2 = (const float*)d_in[9];
  const float* be2 = (const float*)d_in[10];
  const float* W1 = (const float*)d_in[11];
  const float* bf1 = (const float*)d_in[12];
  const float* W2 = (const float*)d_in[13];
  const float* bf2v = (const float*)d_in[14];
  float* out = (float*)d_out;

  char* w = (char*)d_ws;
  size_t off = 0;
  auto alloc = [&](size_t bytes) -> void* {
    void* p = w + off;
    off += (bytes + 255) & ~(size_t)255;
    return p;
  };
  u16* xn_perm = (u16*)alloc(16384ull * 512 * 2);
  u16* xn_res = (u16*)alloc(16384ull * 512 * 2);
  u16* qbuf = (u16*)alloc(128ull * 1024 * 64 * 2);
  u16* kbuf = (u16*)alloc(128ull * 1024 * 64 * 2);
  u16* vtb = (u16*)alloc(128ull * 64 * 1024 * 2);
  u16* wqkv_t = (u16*)alloc(1536ull * 512 * 2);
  u16* w1t = (u16*)alloc(1024ull * 512 * 2);
  u16* w2t = (u16*)alloc(512ull * 1024 * 2);
  float* gram = (float*)alloc(2ull * 128 * 8 * 4096 * 4);
  u16* h_bf = (u16*)gram;  // overlay: gram dead before FFN1 writes h
  float* gram2 = (float*)alloc(2ull * 128 * 8 * 64 * 4);
  float* stats = (float*)alloc(128ull * 2 * 4);
  float* ch = (float*)alloc(64ull * 4);
  u16* ao_bf = (u16*)alloc(16384ull * 512 * 2);
  u16* xt_bf = (u16*)alloc(16384ull * 512 * 2);

  k_transpose<<<dim3(8, 8), 256, 0, stream>>>(Wq, wqkv_t, 512, 512);
  k_transpose<<<dim3(8, 8), 256, 0, stream>>>(Wk, wqkv_t + 512 * 512, 512, 512);
  k_transpose<<<dim3(8, 8), 256, 0, stream>>>(Wv, wqkv_t + 1024 * 512, 512, 512);
  k_transpose<<<dim3(16, 8), 256, 0, stream>>>(W1, w1t, 512, 1024);
  k_transpose<<<dim3(8, 16), 256, 0, stream>>>(W2, w2t, 1024, 512);

  k_ln1<<<4096, 256, 0, stream>>>(x, g1, be1, xn_perm, xn_res);

  k_gemm<0, 128><<<dim3(128, 12), 256, 0, stream>>>(xn_perm, wqkv_t, 512, bq, bk,
                                                    bv, qbuf, kbuf, vtb, nullptr,
                                                    nullptr);

  k_gram<<<dim3(8, 128, 2), 256, 0, stream>>>(qbuf, kbuf, gram, gram2);
  k_gram_reduce<<<128, 256, 0, stream>>>(gram, gram2, stats);
  k_scaling<<<1, 64, 0, stream>>>(stats, ch);

  k_attn<<<dim3(128, 8), 256, 0, stream>>>(qbuf, kbuf, vtb, ch, ao_bf);

  k_ln2<<<4096, 256, 0, stream>>>(xn_res, ao_bf, g2, be2, xt_bf);

  k_gemm<1, 128><<<dim3(128, 8), 256, 0, stream>>>(xt_bf, w1t, 512, bf1, nullptr,
                                                   nullptr, h_bf, nullptr, nullptr,
                                                   nullptr, nullptr);
  k_gemm<2, 64><<<dim3(256, 4), 256, 0, stream>>>(h_bf, w2t, 1024, bf2v, nullptr,
                                                  nullptr, nullptr, nullptr,
                                                  nullptr, xt_bf, out);
  (void)in_sizes; (void)n_in; (void)out_size; (void)ws_size;
}

// Round 6
// 259.530 us; speedup vs baseline: 1.2480x; 1.0026x over previous
//
#include <hip/hip_runtime.h>
#include <stdint.h>

typedef unsigned short u16;
typedef u16 u16x4 __attribute__((ext_vector_type(4)));
typedef unsigned int u32x4 __attribute__((ext_vector_type(4)));
typedef float f32x4 __attribute__((ext_vector_type(4)));
typedef float f32x16 __attribute__((ext_vector_type(16)));
typedef __bf16 bf16x8 __attribute__((ext_vector_type(8)));

#define DEVI __device__ __forceinline__

DEVI u16 f2bf(float f) {
  uint32_t u = __builtin_bit_cast(uint32_t, f);
  u = (u + 0x7FFFu + ((u >> 16) & 1u)) >> 16;
  return (u16)u;
}
DEVI float bf2f(u16 h) {
  uint32_t u = ((uint32_t)h) << 16;
  return __builtin_bit_cast(float, u);
}
DEVI f32x4 mfma16(u32x4 a, u32x4 b, f32x4 c) {
  return __builtin_amdgcn_mfma_f32_16x16x32_bf16(
      __builtin_bit_cast(bf16x8, a), __builtin_bit_cast(bf16x8, b), c, 0, 0, 0);
}
DEVI f32x16 mfma32(u32x4 a, u32x4 b, f32x16 c) {
  return __builtin_amdgcn_mfma_f32_32x32x16_bf16(
      __builtin_bit_cast(bf16x8, a), __builtin_bit_cast(bf16x8, b), c, 0, 0, 0);
}
DEVI uint32_t cvtpk(float lo, float hi) {
  uint32_t w;
  asm("v_cvt_pk_bf16_f32 %0, %1, %2" : "=v"(w) : "v"(lo), "v"(hi));
  return w;
}
DEVI void plswap(uint32_t& a, uint32_t& b) {
  asm("v_permlane32_swap_b32 %0, %1" : "+v"(a), "+v"(b));
}
DEVI float xmax2(float v) {
  uint32_t a = __builtin_bit_cast(uint32_t, v), b = a;
  plswap(a, b);
  return fmaxf(__builtin_bit_cast(float, a), __builtin_bit_cast(float, b));
}

#define AS1 __attribute__((address_space(1)))
#define AS3 __attribute__((address_space(3)))
DEVI void gload16(const void* g, void* l) {
  __builtin_amdgcn_global_load_lds((AS1 void*)(uintptr_t)g,
                                   (AS3 void*)(uint32_t)(uintptr_t)l, 16, 0, 0);
}

DEVI float wred(float v) {
#pragma unroll
  for (int m = 1; m < 64; m <<= 1) v += __shfl_xor(v, m);
  return v;
}

// ---------------- merged weight prep: 5 transposes (fp32 -> bf16, Wt[N][K]=W[K][N])
// in ONE launch. Block table: [0,192) Wq/Wk/Wv (8x8 tiles each), [192,320) W1
// (16x8), [320,448) W2 (8x16).
__global__ __launch_bounds__(256) void k_prep(const float* __restrict__ Wq,
                                              const float* __restrict__ Wk,
                                              const float* __restrict__ Wv,
                                              const float* __restrict__ W1,
                                              const float* __restrict__ W2,
                                              u16* __restrict__ wqkv_t,
                                              u16* __restrict__ w1t,
                                              u16* __restrict__ w2t) {
  __shared__ float tile[64][65];
  int bid = blockIdx.x, tid = threadIdx.x;
  const float* W;
  u16* Wt;
  int Kr, Nc, n0, k0;
  if (bid < 192) {
    int w = bid / 64, t = bid & 63;
    W = (w == 0) ? Wq : (w == 1) ? Wk : Wv;
    Wt = wqkv_t + (size_t)w * 512 * 512;
    Kr = 512; Nc = 512; n0 = (t & 7) * 64; k0 = (t >> 3) * 64;
  } else if (bid < 320) {
    int t = bid - 192;
    W = W1; Wt = w1t;
    Kr = 512; Nc = 1024; n0 = (t & 15) * 64; k0 = (t >> 4) * 64;
  } else {
    int t = bid - 320;
    W = W2; Wt = w2t;
    Kr = 1024; Nc = 512; n0 = (t & 7) * 64; k0 = (t >> 3) * 64;
  }
#pragma unroll
  for (int i = 0; i < 16; i++) {
    int idx = i * 256 + tid;
    int r = idx >> 6, cc = idx & 63;
    tile[r][cc] = W[(size_t)(k0 + r) * Nc + n0 + cc];
  }
  __syncthreads();
#pragma unroll
  for (int i = 0; i < 16; i++) {
    int idx = i * 256 + tid;
    int r = idx >> 6, cc = idx & 63;
    Wt[(size_t)(n0 + r) * Kr + k0 + cc] = f2bf(tile[cc][r]);
  }
}

// ---------------- LN1 ----------------
__global__ __launch_bounds__(256) void k_ln1(const float* __restrict__ x,
                                             const float* __restrict__ gam,
                                             const float* __restrict__ bet,
                                             u16* __restrict__ xn_perm,
                                             u16* __restrict__ xn_res) {
  int tid = threadIdx.x, wid = tid >> 6, lane = tid & 63;
  int row = blockIdx.x * 4 + wid;
  const float* xr = x + (size_t)row * 512 + lane * 8;
  f32x4 v0 = *(const f32x4*)xr;
  f32x4 v1 = *(const f32x4*)(xr + 4);
  float s = 0.f, ss = 0.f;
#pragma unroll
  for (int j = 0; j < 4; j++) {
    s += v0[j] + v1[j];
    ss += v0[j] * v0[j] + v1[j] * v1[j];
  }
  s = wred(s);
  ss = wred(ss);
  float mean = s * (1.0f / 512.0f);
  float var = ss * (1.0f / 512.0f) - mean * mean;
  float rstd = rsqrtf(var + 1e-5f);
  const float* gp = gam + lane * 8;
  const float* bp = bet + lane * 8;
  f32x4 ga = *(const f32x4*)gp, gb = *(const f32x4*)(gp + 4);
  f32x4 ba = *(const f32x4*)bp, bb = *(const f32x4*)(bp + 4);
  u16x4 o0, o1;
#pragma unroll
  for (int j = 0; j < 4; j++) {
    o0[j] = f2bf((v0[j] - mean) * rstd * ga[j] + ba[j]);
    o1[j] = f2bf((v1[j] - mean) * rstd * gb[j] + bb[j]);
  }
  int b = row & 15, a = row >> 4;
  u16* pp = xn_perm + ((size_t)((b << 10) | a)) * 512 + lane * 8;
  *(u16x4*)pp = o0;
  *(u16x4*)(pp + 4) = o1;
  u16* pr = xn_res + (size_t)row * 512 + lane * 8;
  *(u16x4*)pr = o0;
  *(u16x4*)(pr + 4) = o1;
}

// ---------------- LN2 ----------------
__global__ __launch_bounds__(256) void k_ln2(const u16* __restrict__ xn,
                                             const u16* __restrict__ ao,
                                             const float* __restrict__ gam,
                                             const float* __restrict__ bet,
                                             u16* __restrict__ xt) {
  int tid = threadIdx.x, wid = tid >> 6, lane = tid & 63;
  int row = blockIdx.x * 4 + wid;
  size_t base = (size_t)row * 512 + lane * 8;
  u16x4 a0 = *(const u16x4*)&xn[base], a1 = *(const u16x4*)&xn[base + 4];
  u16x4 c0 = *(const u16x4*)&ao[base], c1 = *(const u16x4*)&ao[base + 4];
  float v[8];
#pragma unroll
  for (int j = 0; j < 4; j++) {
    v[j] = bf2f(a0[j]) + bf2f(c0[j]);
    v[4 + j] = bf2f(a1[j]) + bf2f(c1[j]);
  }
  float s = 0.f, ss = 0.f;
#pragma unroll
  for (int j = 0; j < 8; j++) {
    s += v[j];
    ss += v[j] * v[j];
  }
  s = wred(s);
  ss = wred(ss);
  float mean = s * (1.0f / 512.0f);
  float var = ss * (1.0f / 512.0f) - mean * mean;
  float rstd = rsqrtf(var + 1e-5f);
  const float* gp = gam + lane * 8;
  const float* bp = bet + lane * 8;
  u16x4 o0, o1;
#pragma unroll
  for (int j = 0; j < 4; j++) {
    o0[j] = f2bf((v[j] - mean) * rstd * gp[j] + bp[j]);
    o1[j] = f2bf((v[4 + j] - mean) * rstd * gp[4 + j] + bp[4 + j]);
  }
  u16* pr = xt + base;
  *(u16x4*)pr = o0;
  *(u16x4*)(pr + 4) = o1;
}

// ---------------- GEMM C = A * B^T, BM x 128 tile, BK=64, dbuf single-barrier ------
template <int EPI, int BM>
__global__ __launch_bounds__(256, BM == 64 ? 3 : 2) void k_gemm(
    const u16* __restrict__ A, const u16* __restrict__ B, int K,
    const float* __restrict__ b0, const float* __restrict__ b1,
    const float* __restrict__ b2, u16* __restrict__ o0, u16* __restrict__ o1,
    u16* __restrict__ o2, const u16* __restrict__ resid,
    float* __restrict__ outf) {
  constexpr int MI = BM / 32;  // acc rows per wave (of 16)
  __shared__ __align__(16) u16 As[2][BM * 64];
  __shared__ __align__(16) u16 Bs[2][128 * 64];
  const int tid = threadIdx.x;
  const int wid = tid >> 6, lane = tid & 63;
  const int g = lane >> 4, c = lane & 15;
  const int m0 = blockIdx.x * BM, n0 = blockIdx.y * 128;
  const int wr = (wid >> 1) * (BM / 2), wc = (wid & 1) * 64;
  const int srow = tid >> 3, scb = tid & 7;

  f32x4 acc[MI][4];
  const f32x4 zero = {0.f, 0.f, 0.f, 0.f};
#pragma unroll
  for (int i = 0; i < MI; i++)
#pragma unroll
    for (int j = 0; j < 4; j++) acc[i][j] = zero;

  auto stage = [&](int buf, int k0) {
#pragma unroll
    for (int i = 0; i < BM / 32; i++) {
      int row = i * 32 + srow;
      int col = ((scb ^ (row & 7)) << 3);
      gload16(A + (size_t)(m0 + row) * K + k0 + col, &As[buf][(i * 256 + tid) * 8]);
    }
#pragma unroll
    for (int i = 0; i < 4; i++) {
      int row = i * 32 + srow;
      int col = ((scb ^ (row & 7)) << 3);
      gload16(B + (size_t)(n0 + row) * K + k0 + col, &Bs[buf][(i * 256 + tid) * 8]);
    }
  };

  stage(0, 0);
  int cur = 0;
  for (int k0 = 0; k0 < K; k0 += 64) {
    __syncthreads();  // drains vmcnt(0): buf[cur] staged; prev readers done
    if (k0 + 64 < K) stage(cur ^ 1, k0 + 64);
#pragma unroll
    for (int kk = 0; kk < 2; kk++) {
      u32x4 af[MI], bfr[4];
#pragma unroll
      for (int mi = 0; mi < MI; mi++) {
        int row = wr + mi * 16 + c;
        int cb = (kk * 4 + g) ^ (row & 7);
        af[mi] = *(const u32x4*)&As[cur][row * 64 + cb * 8];
      }
#pragma unroll
      for (int ni = 0; ni < 4; ni++) {
        int row = wc + ni * 16 + c;
        int cb = (kk * 4 + g) ^ (row & 7);
        bfr[ni] = *(const u32x4*)&Bs[cur][row * 64 + cb * 8];
      }
#pragma unroll
      for (int mi = 0; mi < MI; mi++)
#pragma unroll
        for (int ni = 0; ni < 4; ni++)
          acc[mi][ni] = mfma16(af[mi], bfr[ni], acc[mi][ni]);
    }
    cur ^= 1;
  }

  if constexpr (EPI == 0) {
#pragma unroll
    for (int mi = 0; mi < MI; mi++) {
#pragma unroll
      for (int ni = 0; ni < 4; ni++) {
        int n = n0 + wc + ni * 16 + c;
        int which = n >> 9, h = (n >> 6) & 7, dh = n & 63;
        const float* bp = (which == 0) ? b0 : (which == 1) ? b1 : b2;
        float bias = bp[n & 511];
        int mbase = m0 + wr + mi * 16 + g * 4;
        int bb = mbase >> 10, aa = mbase & 1023;
        int bh = bb * 8 + h;
        if (which < 2) {
          u16* dst = ((which == 0) ? o0 : o1) + ((size_t)bh * 1024 + aa) * 64 + dh;
#pragma unroll
          for (int r = 0; r < 4; r++) dst[(size_t)r * 64] = f2bf(acc[mi][ni][r] + bias);
        } else {
          u16x4 pk;
#pragma unroll
          for (int r = 0; r < 4; r++) pk[r] = f2bf(acc[mi][ni][r] + bias);
          *(u16x4*)(o2 + ((size_t)bh * 64 + dh) * 1024 + aa) = pk;
        }
      }
    }
  } else if constexpr (EPI == 1) {
#pragma unroll
    for (int mi = 0; mi < MI; mi++) {
#pragma unroll
      for (int ni = 0; ni < 4; ni++) {
        int n = n0 + wc + ni * 16 + c;
        float bias = b0[n];
#pragma unroll
        for (int r = 0; r < 4; r++) {
          int m = m0 + wr + mi * 16 + g * 4 + r;
          float v = acc[mi][ni][r] + bias;
          v = 0.5f * v * (1.0f + erff(v * 0.70710678118654752f));
          o0[(size_t)m * 1024 + n] = f2bf(v);
        }
      }
    }
  } else {
#pragma unroll
    for (int mi = 0; mi < MI; mi++) {
#pragma unroll
      for (int ni = 0; ni < 4; ni++) {
        int n = n0 + wc + ni * 16 + c;
        float bias = b0[n];
#pragma unroll
        for (int r = 0; r < 4; r++) {
          int m = m0 + wr + mi * 16 + g * 4 + r;
          float v = acc[mi][ni][r] + bias + bf2f(resid[(size_t)m * 512 + n]);
          outf[(size_t)m * 512 + n] = v;
        }
      }
    }
  }
}

// ---------------- Gram partials ----------------
__global__ __launch_bounds__(256) void k_gram(const u16* __restrict__ q,
                                              const u16* __restrict__ k,
                                              float* __restrict__ part,
                                              float* __restrict__ part2) {
  __shared__ float T[128 * 64];
  int tid = threadIdx.x;
  int chunk = blockIdx.x, bh = blockIdx.y, which = blockIdx.z;
  const u16* src = (which == 0 ? q : k) + ((size_t)bh * 1024 + chunk * 128) * 64;
#pragma unroll
  for (int i = 0; i < 8; i++) {
    int e = (i * 256 + tid) * 4;
    u16x4 u = *(const u16x4*)&src[e];
    f32x4 f = {bf2f(u[0]), bf2f(u[1]), bf2f(u[2]), bf2f(u[3])};
    *(f32x4*)&T[e] = f;
  }
  __syncthreads();
  int i0 = (tid >> 4) * 4, j0 = (tid & 15) * 4;
  float accg[4][4] = {};
  for (int a = 0; a < 128; a++) {
    f32x4 qi = *(const f32x4*)&T[a * 64 + i0];
    f32x4 qj = *(const f32x4*)&T[a * 64 + j0];
#pragma unroll
    for (int ii = 0; ii < 4; ii++)
#pragma unroll
      for (int jj = 0; jj < 4; jj++) accg[ii][jj] += qi[ii] * qj[jj];
  }
  float* dst = part + ((((size_t)which * 128 + bh) * 8 + chunk) << 12);
#pragma unroll
  for (int ii = 0; ii < 4; ii++)
#pragma unroll
    for (int jj = 0; jj < 4; jj++) dst[(i0 + ii) * 64 + (j0 + jj)] = accg[ii][jj];
  if (tid < 64) {
    float s = 0.f;
    for (int a = 0; a < 128; a++) s += T[a * 64 + tid];
    part2[(((size_t)which * 128 + bh) * 8 + chunk) * 64 + tid] = s;
  }
}

__global__ __launch_bounds__(256) void k_gram_reduce(const float* __restrict__ part,
                                                     const float* __restrict__ part2,
                                                     float* __restrict__ stats) {
  int bh = blockIdx.x, tid = threadIdx.x;
  const float* pq = part + ((size_t)bh << 15);
  const float* pk = part + ((size_t)(128 + bh) << 15);
  float local = 0.f;
#pragma unroll
  for (int j4 = 0; j4 < 4; j4++) {
    int e = tid * 16 + j4 * 4;
    f32x4 gq = {0.f, 0.f, 0.f, 0.f}, gk = {0.f, 0.f, 0.f, 0.f};
#pragma unroll
    for (int cc = 0; cc < 8; cc++) {
      gq += *(const f32x4*)&pq[cc * 4096 + e];
      gk += *(const f32x4*)&pk[cc * 4096 + e];
    }
    f32x4 p = gq * gk;
    local += p[0] + p[1] + p[2] + p[3];
  }
  local = wred(local);
  __shared__ float red[4];
  if ((tid & 63) == 0) red[tid >> 6] = local;
  __syncthreads();
  float sumv = 0.f;
  if (tid < 64) {
    const float* p2q = part2 + (size_t)bh * 512;
    const float* p2k = part2 + (size_t)(128 + bh) * 512;
    float sq = 0.f, sk = 0.f;
#pragma unroll
    for (int cc = 0; cc < 8; cc++) {
      sq += p2q[cc * 64 + tid];
      sk += p2k[cc * 64 + tid];
    }
    sumv = wred(sq * sk);
  }
  if (tid == 0) {
    stats[bh * 2] = red[0] + red[1] + red[2] + red[3];
    stats[bh * 2 + 1] = sumv;
  }
}

__global__ void k_scaling(const float* __restrict__ stats, float* __restrict__ ch) {
  int h = threadIdx.x;
  if (h < 8) {
    float ssq = 0.f, sm = 0.f;
    for (int b = 0; b < 16; b++) {
      ssq += stats[(b * 8 + h) * 2];
      sm += stats[(b * 8 + h) * 2 + 1];
    }
    const float N = 16777216.0f;
    float var = (ssq - sm * sm / N) / (N - 1.0f);
    float sd = sqrtf(fmaxf(var, 0.0f));
    float scal = 8.0f * sqrtf(1.0f + sd);
    ch[h] = 1.4426950408889634f / scal;  // log2(e)/scaling
  }
}

// ---------------- flash attention (unchanged from R5) ----------------
__global__ __launch_bounds__(256, 3) void k_attn(const u16* __restrict__ q,
                                                 const u16* __restrict__ k,
                                                 const u16* __restrict__ vt,
                                                 const float* __restrict__ ch_arr,
                                                 u16* __restrict__ ao) {
  __shared__ __align__(16) u16 Ks[2][64 * 64];
  __shared__ __align__(16) u16 Vs[2][64 * 64];
  int tid = threadIdx.x, wid = tid >> 6, lane = tid & 63;
  int r = lane & 31, hi = lane >> 5, h8 = hi * 8;
  int bh = blockIdx.x, qt = blockIdx.y;
  int b = bh >> 3, h = bh & 7;
  float sc = ch_arr[h];
  int q0 = qt * 128 + wid * 32;
  const u16* qb = q + ((size_t)bh << 16);
  const u16* kb = k + ((size_t)bh << 16);
  const u16* vb = vt + ((size_t)bh << 16);
  const int srow = tid >> 3, scb = tid & 7;
  const u32x4 ones = {0x3F803F80u, 0x3F803F80u, 0x3F803F80u, 0x3F803F80u};

  u32x4 qf[4];
  const u16* qrow = qb + (size_t)(q0 + r) * 64 + h8;
#pragma unroll
  for (int ks = 0; ks < 4; ks++) {
    u32x4 raw = *(const u32x4*)(qrow + ks * 16);
    u32x4 w;
#pragma unroll
    for (int t = 0; t < 4; t++) {
      float lo = bf2f((u16)(raw[t] & 0xffffu)) * sc;
      float hi_ = bf2f((u16)(raw[t] >> 16)) * sc;
      w[t] = cvtpk(lo, hi_);
    }
    qf[ks] = w;
  }

  const f32x16 zero16 = {0.f, 0.f, 0.f, 0.f, 0.f, 0.f, 0.f, 0.f,
                         0.f, 0.f, 0.f, 0.f, 0.f, 0.f, 0.f, 0.f};
  f32x16 o0 = zero16, o1 = zero16, lacc = zero16;
  float m_run = -1e30f;

  auto stage = [&](int buf, int t0) {
#pragma unroll
    for (int i = 0; i < 2; i++) {
      int row = i * 32 + srow;
      int col = ((scb ^ (row & 7)) << 3);
      gload16(kb + (size_t)(t0 + row) * 64 + col, &Ks[buf][(i * 256 + tid) * 8]);
      gload16(vb + (size_t)row * 1024 + t0 + col, &Vs[buf][(i * 256 + tid) * 8]);
    }
  };

  stage(0, 0);
  int cur = 0;
  for (int t0 = 0; t0 < 1024; t0 += 64) {
    __syncthreads();
    if (t0 + 64 < 1024) stage(cur ^ 1, t0 + 64);
    const u16* Kc = Ks[cur];
    const u16* Vc = Vs[cur];
#pragma unroll
    for (int ss = 0; ss < 2; ss++) {
      f32x16 st = zero16;
      int rk = ss * 32 + r;
      __builtin_amdgcn_s_setprio(1);
#pragma unroll
      for (int ks = 0; ks < 4; ks++) {
        int cb = (ks * 2 + hi) ^ (rk & 7);
        u32x4 kf = *(const u32x4*)&Kc[rk * 64 + cb * 8];
        st = mfma32(kf, qf[ks], st);
      }
      __builtin_amdgcn_s_setprio(0);
      float mx[8];
#pragma unroll
      for (int i = 0; i < 8; i++) mx[i] = fmaxf(st[i], st[i + 8]);
#pragma unroll
      for (int i = 0; i < 4; i++) mx[i] = fmaxf(mx[i], mx[i + 4]);
      float pm = fmaxf(fmaxf(mx[0], mx[2]), fmaxf(mx[1], mx[3]));
      pm = xmax2(pm);
      if (__any(pm > m_run + 8.0f)) {
        float mnew = fmaxf(m_run, pm);
        float al = exp2f(m_run - mnew);
        lacc[0] *= al;
#pragma unroll
        for (int i = 0; i < 16; i++) {
          o0[i] *= al;
          o1[i] *= al;
        }
        m_run = mnew;
      }
      float p[16];
#pragma unroll
      for (int i = 0; i < 16; i++) p[i] = exp2f(st[i] - m_run);
      __builtin_amdgcn_s_setprio(1);
#pragma unroll
      for (int ks = 0; ks < 2; ks++) {
        uint32_t A0 = cvtpk(p[ks * 8 + 0], p[ks * 8 + 1]);
        uint32_t A1 = cvtpk(p[ks * 8 + 4], p[ks * 8 + 5]);
        plswap(A0, A1);
        uint32_t B0 = cvtpk(p[ks * 8 + 2], p[ks * 8 + 3]);
        uint32_t B1 = cvtpk(p[ks * 8 + 6], p[ks * 8 + 7]);
        plswap(B0, B1);
        u32x4 pa = {A0, B0, A1, B1};
        lacc = mfma32(ones, pa, lacc);
#pragma unroll
        for (int mt = 0; mt < 2; mt++) {
          int rv = mt * 32 + r;
          int cb = (ss * 4 + ks * 2 + hi) ^ (rv & 7);
          u32x4 vf = *(const u32x4*)&Vc[rv * 64 + cb * 8];
          if (mt == 0)
            o0 = mfma32(vf, pa, o0);
          else
            o1 = mfma32(vf, pa, o1);
        }
      }
      __builtin_amdgcn_s_setprio(0);
    }
    cur ^= 1;
  }

  float inv = 1.0f / lacc[0];
  int a_idx = q0 + r;
  u16* aop = ao + ((size_t)(a_idx * 16 + b)) * 512 + h * 64;
#pragma unroll
  for (int i = 0; i < 16; i++) {
    int dh0 = (i & 3) + 8 * (i >> 2) + 4 * hi;
    aop[dh0] = f2bf(o0[i] * inv);
    aop[32 + dh0] = f2bf(o1[i] * inv);
  }
}

extern "C" void kernel_launch(void* const* d_in, const int* in_sizes, int n_in,
                              void* d_out, int out_size, void* d_ws, size_t ws_size,
                              hipStream_t stream) {
  const float* x = (const float*)d_in[0];
  const float* Wq = (const float*)d_in[1];
  const float* bq = (const float*)d_in[2];
  const float* Wk = (const float*)d_in[3];
  const float* bk = (const float*)d_in[4];
  const float* Wv = (const float*)d_in[5];
  const float* bv = (const float*)d_in[6];
  const float* g1 = (const float*)d_in[7];
  const float* be1 = (const float*)d_in[8];
  const float* g2 = (const float*)d_in[9];
  const float* be2 = (const float*)d_in[10];
  const float* W1 = (const float*)d_in[11];
  const float* bf1 = (const float*)d_in[12];
  const float* W2 = (const float*)d_in[13];
  const float* bf2v = (const float*)d_in[14];
  float* out = (float*)d_out;

  char* w = (char*)d_ws;
  size_t off = 0;
  auto alloc = [&](size_t bytes) -> void* {
    void* p = w + off;
    off += (bytes + 255) & ~(size_t)255;
    return p;
  };
  u16* xn_perm = (u16*)alloc(16384ull * 512 * 2);
  u16* xn_res = (u16*)alloc(16384ull * 512 * 2);
  u16* qbuf = (u16*)alloc(128ull * 1024 * 64 * 2);
  u16* kbuf = (u16*)alloc(128ull * 1024 * 64 * 2);
  u16* vtb = (u16*)alloc(128ull * 64 * 1024 * 2);
  u16* wqkv_t = (u16*)alloc(1536ull * 512 * 2);
  u16* w1t = (u16*)alloc(1024ull * 512 * 2);
  u16* w2t = (u16*)alloc(512ull * 1024 * 2);
  float* gram = (float*)alloc(2ull * 128 * 8 * 4096 * 4);
  u16* h_bf = (u16*)gram;  // overlay: gram dead before FFN1 writes h
  float* gram2 = (float*)alloc(2ull * 128 * 8 * 64 * 4);
  float* stats = (float*)alloc(128ull * 2 * 4);
  float* ch = (float*)alloc(64ull * 4);
  u16* ao_bf = (u16*)alloc(16384ull * 512 * 2);
  u16* xt_bf = (u16*)alloc(16384ull * 512 * 2);

  k_prep<<<448, 256, 0, stream>>>(Wq, Wk, Wv, W1, W2, wqkv_t, w1t, w2t);

  k_ln1<<<4096, 256, 0, stream>>>(x, g1, be1, xn_perm, xn_res);

  k_gemm<0, 128><<<dim3(128, 12), 256, 0, stream>>>(xn_perm, wqkv_t, 512, bq, bk,
                                                    bv, qbuf, kbuf, vtb, nullptr,
                                                    nullptr);

  k_gram<<<dim3(8, 128, 2), 256, 0, stream>>>(qbuf, kbuf, gram, gram2);
  k_gram_reduce<<<128, 256, 0, stream>>>(gram, gram2, stats);
  k_scaling<<<1, 64, 0, stream>>>(stats, ch);

  k_attn<<<dim3(128, 8), 256, 0, stream>>>(qbuf, kbuf, vtb, ch, ao_bf);

  k_ln2<<<4096, 256, 0, stream>>>(xn_res, ao_bf, g2, be2, xt_bf);

  k_gemm<1, 128><<<dim3(128, 8), 256, 0, stream>>>(xt_bf, w1t, 512, bf1, nullptr,
                                                   nullptr, h_bf, nullptr, nullptr,
                                                   nullptr, nullptr);
  k_gemm<2, 64><<<dim3(256, 4), 256, 0, stream>>>(h_bf, w2t, 1024, bf2v, nullptr,
                                                  nullptr, nullptr, nullptr,
                                                  nullptr, xt_bf, out);
  (void)in_sizes; (void)n_in; (void)out_size; (void)ws_size;
}

// Round 7
// 239.961 us; speedup vs baseline: 1.3497x; 1.0816x over previous
//
#include <hip/hip_runtime.h>
#include <stdint.h>

typedef unsigned short u16;
typedef u16 u16x4 __attribute__((ext_vector_type(4)));
typedef unsigned int u32x4 __attribute__((ext_vector_type(4)));
typedef float f32x4 __attribute__((ext_vector_type(4)));
typedef float f32x16 __attribute__((ext_vector_type(16)));
typedef __bf16 bf16x8 __attribute__((ext_vector_type(8)));

#define DEVI __device__ __forceinline__

DEVI u16 f2bf(float f) {
  uint32_t u = __builtin_bit_cast(uint32_t, f);
  u = (u + 0x7FFFu + ((u >> 16) & 1u)) >> 16;
  return (u16)u;
}
DEVI float bf2f(u16 h) {
  uint32_t u = ((uint32_t)h) << 16;
  return __builtin_bit_cast(float, u);
}
DEVI f32x4 mfma16(u32x4 a, u32x4 b, f32x4 c) {
  return __builtin_amdgcn_mfma_f32_16x16x32_bf16(
      __builtin_bit_cast(bf16x8, a), __builtin_bit_cast(bf16x8, b), c, 0, 0, 0);
}
DEVI f32x16 mfma32(u32x4 a, u32x4 b, f32x16 c) {
  return __builtin_amdgcn_mfma_f32_32x32x16_bf16(
      __builtin_bit_cast(bf16x8, a), __builtin_bit_cast(bf16x8, b), c, 0, 0, 0);
}
DEVI uint32_t cvtpk(float lo, float hi) {
  uint32_t w;
  asm("v_cvt_pk_bf16_f32 %0, %1, %2" : "=v"(w) : "v"(lo), "v"(hi));
  return w;
}
DEVI void plswap(uint32_t& a, uint32_t& b) {
  asm("v_permlane32_swap_b32 %0, %1" : "+v"(a), "+v"(b));
}
DEVI float xmax2(float v) {
  uint32_t a = __builtin_bit_cast(uint32_t, v), b = a;
  plswap(a, b);
  return fmaxf(__builtin_bit_cast(float, a), __builtin_bit_cast(float, b));
}

#define AS1 __attribute__((address_space(1)))
#define AS3 __attribute__((address_space(3)))
DEVI void gload16(const void* g, void* l) {
  __builtin_amdgcn_global_load_lds((AS1 void*)(uintptr_t)g,
                                   (AS3 void*)(uint32_t)(uintptr_t)l, 16, 0, 0);
}

DEVI float wred(float v) {
#pragma unroll
  for (int m = 1; m < 64; m <<= 1) v += __shfl_xor(v, m);
  return v;
}

// ---------------- merged weight prep: 5 transposes (fp32 -> bf16) in ONE launch ----
__global__ __launch_bounds__(256) void k_prep(const float* __restrict__ Wq,
                                              const float* __restrict__ Wk,
                                              const float* __restrict__ Wv,
                                              const float* __restrict__ W1,
                                              const float* __restrict__ W2,
                                              u16* __restrict__ wqkv_t,
                                              u16* __restrict__ w1t,
                                              u16* __restrict__ w2t) {
  __shared__ float tile[64][65];
  int bid = blockIdx.x, tid = threadIdx.x;
  const float* W;
  u16* Wt;
  int Kr, Nc, n0, k0;
  if (bid < 192) {
    int w = bid / 64, t = bid & 63;
    W = (w == 0) ? Wq : (w == 1) ? Wk : Wv;
    Wt = wqkv_t + (size_t)w * 512 * 512;
    Kr = 512; Nc = 512; n0 = (t & 7) * 64; k0 = (t >> 3) * 64;
  } else if (bid < 320) {
    int t = bid - 192;
    W = W1; Wt = w1t;
    Kr = 512; Nc = 1024; n0 = (t & 15) * 64; k0 = (t >> 4) * 64;
  } else {
    int t = bid - 320;
    W = W2; Wt = w2t;
    Kr = 1024; Nc = 512; n0 = (t & 7) * 64; k0 = (t >> 3) * 64;
  }
#pragma unroll
  for (int i = 0; i < 16; i++) {
    int idx = i * 256 + tid;
    int r = idx >> 6, cc = idx & 63;
    tile[r][cc] = W[(size_t)(k0 + r) * Nc + n0 + cc];
  }
  __syncthreads();
#pragma unroll
  for (int i = 0; i < 16; i++) {
    int idx = i * 256 + tid;
    int r = idx >> 6, cc = idx & 63;
    Wt[(size_t)(n0 + r) * Kr + k0 + cc] = f2bf(tile[cc][r]);
  }
}

// ---------------- LN1: x[a,b,512] -> xn[token=a*16+b][512] bf16 (single output) -----
__global__ __launch_bounds__(256) void k_ln1(const float* __restrict__ x,
                                             const float* __restrict__ gam,
                                             const float* __restrict__ bet,
                                             u16* __restrict__ xn_res) {
  int tid = threadIdx.x, wid = tid >> 6, lane = tid & 63;
  int row = blockIdx.x * 4 + wid;
  const float* xr = x + (size_t)row * 512 + lane * 8;
  f32x4 v0 = *(const f32x4*)xr;
  f32x4 v1 = *(const f32x4*)(xr + 4);
  float s = 0.f, ss = 0.f;
#pragma unroll
  for (int j = 0; j < 4; j++) {
    s += v0[j] + v1[j];
    ss += v0[j] * v0[j] + v1[j] * v1[j];
  }
  s = wred(s);
  ss = wred(ss);
  float mean = s * (1.0f / 512.0f);
  float var = ss * (1.0f / 512.0f) - mean * mean;
  float rstd = rsqrtf(var + 1e-5f);
  const float* gp = gam + lane * 8;
  const float* bp = bet + lane * 8;
  f32x4 ga = *(const f32x4*)gp, gb = *(const f32x4*)(gp + 4);
  f32x4 ba = *(const f32x4*)bp, bb = *(const f32x4*)(bp + 4);
  u16x4 o0, o1;
#pragma unroll
  for (int j = 0; j < 4; j++) {
    o0[j] = f2bf((v0[j] - mean) * rstd * ga[j] + ba[j]);
    o1[j] = f2bf((v1[j] - mean) * rstd * gb[j] + bb[j]);
  }
  u16* pr = xn_res + (size_t)row * 512 + lane * 8;
  *(u16x4*)pr = o0;
  *(u16x4*)(pr + 4) = o1;
}

// ---------------- LN2 ----------------
__global__ __launch_bounds__(256) void k_ln2(const u16* __restrict__ xn,
                                             const u16* __restrict__ ao,
                                             const float* __restrict__ gam,
                                             const float* __restrict__ bet,
                                             u16* __restrict__ xt) {
  int tid = threadIdx.x, wid = tid >> 6, lane = tid & 63;
  int row = blockIdx.x * 4 + wid;
  size_t base = (size_t)row * 512 + lane * 8;
  u16x4 a0 = *(const u16x4*)&xn[base], a1 = *(const u16x4*)&xn[base + 4];
  u16x4 c0 = *(const u16x4*)&ao[base], c1 = *(const u16x4*)&ao[base + 4];
  float v[8];
#pragma unroll
  for (int j = 0; j < 4; j++) {
    v[j] = bf2f(a0[j]) + bf2f(c0[j]);
    v[4 + j] = bf2f(a1[j]) + bf2f(c1[j]);
  }
  float s = 0.f, ss = 0.f;
#pragma unroll
  for (int j = 0; j < 8; j++) {
    s += v[j];
    ss += v[j] * v[j];
  }
  s = wred(s);
  ss = wred(ss);
  float mean = s * (1.0f / 512.0f);
  float var = ss * (1.0f / 512.0f) - mean * mean;
  float rstd = rsqrtf(var + 1e-5f);
  const float* gp = gam + lane * 8;
  const float* bp = bet + lane * 8;
  u16x4 o0, o1;
#pragma unroll
  for (int j = 0; j < 4; j++) {
    o0[j] = f2bf((v[j] - mean) * rstd * gp[j] + bp[j]);
    o1[j] = f2bf((v[4 + j] - mean) * rstd * gp[4 + j] + bp[4 + j]);
  }
  u16* pr = xt + base;
  *(u16x4*)pr = o0;
  *(u16x4*)(pr + 4) = o1;
}

// ---------------- GEMM C = A * B^T, BM x 128 tile, BK=64 ----------------
// EPI0: A-row permutation folded into staging (token -> b*1024+a order);
//       writes q,k row-major AND qt,kt transposed (for gram), vt transposed.
template <int EPI, int BM>
__global__ __launch_bounds__(256, BM == 64 ? 3 : 2) void k_gemm(
    const u16* __restrict__ A, const u16* __restrict__ B, int K,
    const float* __restrict__ b0, const float* __restrict__ b1,
    const float* __restrict__ b2, u16* __restrict__ o0, u16* __restrict__ o1,
    u16* __restrict__ o2, u16* __restrict__ qt, u16* __restrict__ kt,
    const u16* __restrict__ resid, float* __restrict__ outf) {
  constexpr int MI = BM / 32;
  __shared__ __align__(16) u16 As[2][BM * 64];
  __shared__ __align__(16) u16 Bs[2][128 * 64];
  const int tid = threadIdx.x;
  const int wid = tid >> 6, lane = tid & 63;
  const int g = lane >> 4, c = lane & 15;
  const int m0 = blockIdx.x * BM, n0 = blockIdx.y * 128;
  const int wr = (wid >> 1) * (BM / 2), wc = (wid & 1) * 64;
  const int srow = tid >> 3, scb = tid & 7;

  f32x4 acc[MI][4];
  const f32x4 zero = {0.f, 0.f, 0.f, 0.f};
#pragma unroll
  for (int i = 0; i < MI; i++)
#pragma unroll
    for (int j = 0; j < 4; j++) acc[i][j] = zero;

  auto stage = [&](int buf, int k0) {
#pragma unroll
    for (int i = 0; i < BM / 32; i++) {
      int row = i * 32 + srow;
      int col = ((scb ^ (row & 7)) << 3);
      const u16* asrc;
      if constexpr (EPI == 0) {
        int m = m0 + row;  // m = b*1024+a; source row = token a*16+b
        asrc = A + ((size_t)(((m & 1023) << 4) | (m >> 10))) * K + k0 + col;
      } else {
        asrc = A + (size_t)(m0 + row) * K + k0 + col;
      }
      gload16(asrc, &As[buf][(i * 256 + tid) * 8]);
    }
#pragma unroll
    for (int i = 0; i < 4; i++) {
      int row = i * 32 + srow;
      int col = ((scb ^ (row & 7)) << 3);
      gload16(B + (size_t)(n0 + row) * K + k0 + col, &Bs[buf][(i * 256 + tid) * 8]);
    }
  };

  stage(0, 0);
  int cur = 0;
  for (int k0 = 0; k0 < K; k0 += 64) {
    __syncthreads();  // drains vmcnt(0): buf[cur] staged; prev readers done
    if (k0 + 64 < K) stage(cur ^ 1, k0 + 64);
#pragma unroll
    for (int kk = 0; kk < 2; kk++) {
      u32x4 af[MI], bfr[4];
#pragma unroll
      for (int mi = 0; mi < MI; mi++) {
        int row = wr + mi * 16 + c;
        int cb = (kk * 4 + g) ^ (row & 7);
        af[mi] = *(const u32x4*)&As[cur][row * 64 + cb * 8];
      }
#pragma unroll
      for (int ni = 0; ni < 4; ni++) {
        int row = wc + ni * 16 + c;
        int cb = (kk * 4 + g) ^ (row & 7);
        bfr[ni] = *(const u32x4*)&Bs[cur][row * 64 + cb * 8];
      }
#pragma unroll
      for (int mi = 0; mi < MI; mi++)
#pragma unroll
        for (int ni = 0; ni < 4; ni++)
          acc[mi][ni] = mfma16(af[mi], bfr[ni], acc[mi][ni]);
    }
    cur ^= 1;
  }

  if constexpr (EPI == 0) {
#pragma unroll
    for (int mi = 0; mi < MI; mi++) {
#pragma unroll
      for (int ni = 0; ni < 4; ni++) {
        int n = n0 + wc + ni * 16 + c;
        int which = n >> 9, h = (n >> 6) & 7, dh = n & 63;
        const float* bp = (which == 0) ? b0 : (which == 1) ? b1 : b2;
        float bias = bp[n & 511];
        int mbase = m0 + wr + mi * 16 + g * 4;
        int bb = mbase >> 10, aa = mbase & 1023;
        int bh = bb * 8 + h;
        u16x4 pk;
#pragma unroll
        for (int r = 0; r < 4; r++) pk[r] = f2bf(acc[mi][ni][r] + bias);
        if (which < 2) {
          u16* dstr = ((which == 0) ? o0 : o1) + ((size_t)bh * 1024 + aa) * 64 + dh;
#pragma unroll
          for (int r = 0; r < 4; r++) dstr[(size_t)r * 64] = pk[r];
          u16* dstt = ((which == 0) ? qt : kt) + ((size_t)bh * 64 + dh) * 1024 + aa;
          *(u16x4*)dstt = pk;
        } else {
          *(u16x4*)(o2 + ((size_t)bh * 64 + dh) * 1024 + aa) = pk;
        }
      }
    }
  } else if constexpr (EPI == 1) {
#pragma unroll
    for (int mi = 0; mi < MI; mi++) {
#pragma unroll
      for (int ni = 0; ni < 4; ni++) {
        int n = n0 + wc + ni * 16 + c;
        float bias = b0[n];
#pragma unroll
        for (int r = 0; r < 4; r++) {
          int m = m0 + wr + mi * 16 + g * 4 + r;
          float v = acc[mi][ni][r] + bias;
          v = 0.5f * v * (1.0f + erff(v * 0.70710678118654752f));
          o0[(size_t)m * 1024 + n] = f2bf(v);
        }
      }
    }
  } else {
#pragma unroll
    for (int mi = 0; mi < MI; mi++) {
#pragma unroll
      for (int ni = 0; ni < 4; ni++) {
        int n = n0 + wc + ni * 16 + c;
        float bias = b0[n];
#pragma unroll
        for (int r = 0; r < 4; r++) {
          int m = m0 + wr + mi * 16 + g * 4 + r;
          float v = acc[mi][ni][r] + bias + bf2f(resid[(size_t)m * 512 + n]);
          outf[(size_t)m * 512 + n] = v;
        }
      }
    }
  }
}

// ---------------- fused MFMA gram + reduce: one block per bh ----------------
// G = Xt . Xt^T (Xt = [64 dh][1024 a] bf16). ssq = <Gq,Gk>_F; colsums via
// mfma16(af, ones) (all output cols equal the row-sum). Gq stashed in regs.
__global__ __launch_bounds__(256) void k_gram2(const u16* __restrict__ qt,
                                               const u16* __restrict__ kt,
                                               float* __restrict__ stats) {
  __shared__ __align__(16) u16 Xs[64 * 64];
  __shared__ float red[8];
  int tid = threadIdx.x, wid = tid >> 6, lane = tid & 63;
  int g = lane >> 4, c = lane & 15;
  int bh = blockIdx.x;
  const int srow = tid >> 3, scb = tid & 7;
  const u32x4 ones = {0x3F803F80u, 0x3F803F80u, 0x3F803F80u, 0x3F803F80u};
  const f32x4 zero = {0.f, 0.f, 0.f, 0.f};

  f32x4 gq[4], acc[4], sqv = zero, skv = zero;
#pragma unroll
  for (int j = 0; j < 4; j++) gq[j] = zero;

  for (int which = 0; which < 2; which++) {
    const u16* src = (which ? kt : qt) + ((size_t)bh << 16);
#pragma unroll
    for (int j = 0; j < 4; j++) acc[j] = zero;
    f32x4 cs = zero;
    for (int k0 = 0; k0 < 1024; k0 += 64) {
      __syncthreads();
#pragma unroll
      for (int i = 0; i < 2; i++) {
        int row = i * 32 + srow;
        int col = ((scb ^ (row & 7)) << 3);
        gload16(src + (size_t)row * 1024 + k0 + col, &Xs[(i * 256 + tid) * 8]);
      }
      __syncthreads();
#pragma unroll
      for (int kk = 0; kk < 2; kk++) {
        int arow = wid * 16 + c;
        int cba = (kk * 4 + g) ^ (arow & 7);
        u32x4 af = *(const u32x4*)&Xs[arow * 64 + cba * 8];
        cs = mfma16(af, ones, cs);
#pragma unroll
        for (int ni = 0; ni < 4; ni++) {
          int brow = ni * 16 + c;
          int cbb = (kk * 4 + g) ^ (brow & 7);
          u32x4 bf = *(const u32x4*)&Xs[brow * 64 + cbb * 8];
          acc[ni] = mfma16(af, bf, acc[ni]);
        }
      }
    }
    if (which == 0) {
#pragma unroll
      for (int j = 0; j < 4; j++) gq[j] = acc[j];
      sqv = cs;
    } else {
      skv = cs;
    }
  }
  // Frobenius partial: each lane holds 16 unique G elems (rows wid*16+g*4+r, cols ni*16+c)
  float part = 0.f;
#pragma unroll
  for (int ni = 0; ni < 4; ni++)
#pragma unroll
    for (int r = 0; r < 4; r++) part += gq[ni][r] * acc[ni][r];
  part = wred(part);
  // colsum dot: rows wid*16+g*4+r; all cols hold identical value -> count only c==0
  float cpart = 0.f;
  if (c == 0) {
#pragma unroll
    for (int r = 0; r < 4; r++) cpart += sqv[r] * skv[r];
  }
  cpart = wred(cpart);
  if (lane == 0) {
    red[wid] = part;
    red[4 + wid] = cpart;
  }
  __syncthreads();
  if (tid == 0) {
    stats[bh * 2] = red[0] + red[1] + red[2] + red[3];
    stats[bh * 2 + 1] = red[4] + red[5] + red[6] + red[7];
  }
}

__global__ void k_scaling(const float* __restrict__ stats, float* __restrict__ ch) {
  int h = threadIdx.x;
  if (h < 8) {
    float ssq = 0.f, sm = 0.f;
    for (int b = 0; b < 16; b++) {
      ssq += stats[(b * 8 + h) * 2];
      sm += stats[(b * 8 + h) * 2 + 1];
    }
    const float N = 16777216.0f;
    float var = (ssq - sm * sm / N) / (N - 1.0f);
    float sd = sqrtf(fmaxf(var, 0.0f));
    float scal = 8.0f * sqrtf(1.0f + sd);
    ch[h] = 1.4426950408889634f / scal;  // log2(e)/scaling
  }
}

// ---------------- flash attention (unchanged from R5) ----------------
__global__ __launch_bounds__(256, 3) void k_attn(const u16* __restrict__ q,
                                                 const u16* __restrict__ k,
                                                 const u16* __restrict__ vt,
                                                 const float* __restrict__ ch_arr,
                                                 u16* __restrict__ ao) {
  __shared__ __align__(16) u16 Ks[2][64 * 64];
  __shared__ __align__(16) u16 Vs[2][64 * 64];
  int tid = threadIdx.x, wid = tid >> 6, lane = tid & 63;
  int r = lane & 31, hi = lane >> 5, h8 = hi * 8;
  int bh = blockIdx.x, qt = blockIdx.y;
  int b = bh >> 3, h = bh & 7;
  float sc = ch_arr[h];
  int q0 = qt * 128 + wid * 32;
  const u16* qb = q + ((size_t)bh << 16);
  const u16* kb = k + ((size_t)bh << 16);
  const u16* vb = vt + ((size_t)bh << 16);
  const int srow = tid >> 3, scb = tid & 7;
  const u32x4 ones = {0x3F803F80u, 0x3F803F80u, 0x3F803F80u, 0x3F803F80u};

  u32x4 qf[4];
  const u16* qrow = qb + (size_t)(q0 + r) * 64 + h8;
#pragma unroll
  for (int ks = 0; ks < 4; ks++) {
    u32x4 raw = *(const u32x4*)(qrow + ks * 16);
    u32x4 w;
#pragma unroll
    for (int t = 0; t < 4; t++) {
      float lo = bf2f((u16)(raw[t] & 0xffffu)) * sc;
      float hi_ = bf2f((u16)(raw[t] >> 16)) * sc;
      w[t] = cvtpk(lo, hi_);
    }
    qf[ks] = w;
  }

  const f32x16 zero16 = {0.f, 0.f, 0.f, 0.f, 0.f, 0.f, 0.f, 0.f,
                         0.f, 0.f, 0.f, 0.f, 0.f, 0.f, 0.f, 0.f};
  f32x16 o0 = zero16, o1 = zero16, lacc = zero16;
  float m_run = -1e30f;

  auto stage = [&](int buf, int t0) {
#pragma unroll
    for (int i = 0; i < 2; i++) {
      int row = i * 32 + srow;
      int col = ((scb ^ (row & 7)) << 3);
      gload16(kb + (size_t)(t0 + row) * 64 + col, &Ks[buf][(i * 256 + tid) * 8]);
      gload16(vb + (size_t)row * 1024 + t0 + col, &Vs[buf][(i * 256 + tid) * 8]);
    }
  };

  stage(0, 0);
  int cur = 0;
  for (int t0 = 0; t0 < 1024; t0 += 64) {
    __syncthreads();
    if (t0 + 64 < 1024) stage(cur ^ 1, t0 + 64);
    const u16* Kc = Ks[cur];
    const u16* Vc = Vs[cur];
#pragma unroll
    for (int ss = 0; ss < 2; ss++) {
      f32x16 st = zero16;
      int rk = ss * 32 + r;
      __builtin_amdgcn_s_setprio(1);
#pragma unroll
      for (int ks = 0; ks < 4; ks++) {
        int cb = (ks * 2 + hi) ^ (rk & 7);
        u32x4 kf = *(const u32x4*)&Kc[rk * 64 + cb * 8];
        st = mfma32(kf, qf[ks], st);
      }
      __builtin_amdgcn_s_setprio(0);
      float mx[8];
#pragma unroll
      for (int i = 0; i < 8; i++) mx[i] = fmaxf(st[i], st[i + 8]);
#pragma unroll
      for (int i = 0; i < 4; i++) mx[i] = fmaxf(mx[i], mx[i + 4]);
      float pm = fmaxf(fmaxf(mx[0], mx[2]), fmaxf(mx[1], mx[3]));
      pm = xmax2(pm);
      if (__any(pm > m_run + 8.0f)) {
        float mnew = fmaxf(m_run, pm);
        float al = exp2f(m_run - mnew);
        lacc[0] *= al;
#pragma unroll
        for (int i = 0; i < 16; i++) {
          o0[i] *= al;
          o1[i] *= al;
        }
        m_run = mnew;
      }
      float p[16];
#pragma unroll
      for (int i = 0; i < 16; i++) p[i] = exp2f(st[i] - m_run);
      __builtin_amdgcn_s_setprio(1);
#pragma unroll
      for (int ks = 0; ks < 2; ks++) {
        uint32_t A0 = cvtpk(p[ks * 8 + 0], p[ks * 8 + 1]);
        uint32_t A1 = cvtpk(p[ks * 8 + 4], p[ks * 8 + 5]);
        plswap(A0, A1);
        uint32_t B0 = cvtpk(p[ks * 8 + 2], p[ks * 8 + 3]);
        uint32_t B1 = cvtpk(p[ks * 8 + 6], p[ks * 8 + 7]);
        plswap(B0, B1);
        u32x4 pa = {A0, B0, A1, B1};
        lacc = mfma32(ones, pa, lacc);
#pragma unroll
        for (int mt = 0; mt < 2; mt++) {
          int rv = mt * 32 + r;
          int cb = (ss * 4 + ks * 2 + hi) ^ (rv & 7);
          u32x4 vf = *(const u32x4*)&Vc[rv * 64 + cb * 8];
          if (mt == 0)
            o0 = mfma32(vf, pa, o0);
          else
            o1 = mfma32(vf, pa, o1);
        }
      }
      __builtin_amdgcn_s_setprio(0);
    }
    cur ^= 1;
  }

  float inv = 1.0f / lacc[0];
  int a_idx = q0 + r;
  u16* aop = ao + ((size_t)(a_idx * 16 + b)) * 512 + h * 64;
#pragma unroll
  for (int i = 0; i < 16; i++) {
    int dh0 = (i & 3) + 8 * (i >> 2) + 4 * hi;
    aop[dh0] = f2bf(o0[i] * inv);
    aop[32 + dh0] = f2bf(o1[i] * inv);
  }
}

extern "C" void kernel_launch(void* const* d_in, const int* in_sizes, int n_in,
                              void* d_out, int out_size, void* d_ws, size_t ws_size,
                              hipStream_t stream) {
  const float* x = (const float*)d_in[0];
  const float* Wq = (const float*)d_in[1];
  const float* bq = (const float*)d_in[2];
  const float* Wk = (const float*)d_in[3];
  const float* bk = (const float*)d_in[4];
  const float* Wv = (const float*)d_in[5];
  const float* bv = (const float*)d_in[6];
  const float* g1 = (const float*)d_in[7];
  const float* be1 = (const float*)d_in[8];
  const float* g2 = (const float*)d_in[9];
  const float* be2 = (const float*)d_in[10];
  const float* W1 = (const float*)d_in[11];
  const float* bf1 = (const float*)d_in[12];
  const float* W2 = (const float*)d_in[13];
  const float* bf2v = (const float*)d_in[14];
  float* out = (float*)d_out;

  char* w = (char*)d_ws;
  size_t off = 0;
  auto alloc = [&](size_t bytes) -> void* {
    void* p = w + off;
    off += (bytes + 255) & ~(size_t)255;
    return p;
  };
  u16* xn_res = (u16*)alloc(16384ull * 512 * 2);
  u16* qbuf = (u16*)alloc(128ull * 1024 * 64 * 2);
  u16* kbuf = (u16*)alloc(128ull * 1024 * 64 * 2);
  u16* vtb = (u16*)alloc(128ull * 64 * 1024 * 2);
  u16* qtb = (u16*)alloc(128ull * 64 * 1024 * 2);
  u16* ktb = (u16*)alloc(128ull * 64 * 1024 * 2);
  u16* wqkv_t = (u16*)alloc(1536ull * 512 * 2);
  u16* w1t = (u16*)alloc(1024ull * 512 * 2);
  u16* w2t = (u16*)alloc(512ull * 1024 * 2);
  u16* h_bf = (u16*)alloc(16384ull * 1024 * 2);
  float* stats = (float*)alloc(128ull * 2 * 4);
  float* ch = (float*)alloc(64ull * 4);
  u16* ao_bf = (u16*)alloc(16384ull * 512 * 2);
  u16* xt_bf = (u16*)alloc(16384ull * 512 * 2);

  k_prep<<<448, 256, 0, stream>>>(Wq, Wk, Wv, W1, W2, wqkv_t, w1t, w2t);

  k_ln1<<<4096, 256, 0, stream>>>(x, g1, be1, xn_res);

  k_gemm<0, 128><<<dim3(128, 12), 256, 0, stream>>>(
      xn_res, wqkv_t, 512, bq, bk, bv, qbuf, kbuf, vtb, qtb, ktb, nullptr,
      nullptr);

  k_gram2<<<128, 256, 0, stream>>>(qtb, ktb, stats);
  k_scaling<<<1, 64, 0, stream>>>(stats, ch);

  k_attn<<<dim3(128, 8), 256, 0, stream>>>(qbuf, kbuf, vtb, ch, ao_bf);

  k_ln2<<<4096, 256, 0, stream>>>(xn_res, ao_bf, g2, be2, xt_bf);

  k_gemm<1, 128><<<dim3(128, 8), 256, 0, stream>>>(
      xt_bf, w1t, 512, bf1, nullptr, nullptr, h_bf, nullptr, nullptr, nullptr,
      nullptr, nullptr, nullptr);
  k_gemm<2, 64><<<dim3(256, 4), 256, 0, stream>>>(
      h_bf, w2t, 1024, bf2v, nullptr, nullptr, nullptr, nullptr, nullptr,
      nullptr, nullptr, xt_bf, out);
  (void)in_sizes; (void)n_in; (void)out_size; (void)ws_size;
}